// Round 6
// baseline (722.682 us; speedup 1.0000x reference)
//
#include <hip/hip_runtime.h>
#include <math.h>

#define EMB_D 64
#define MARGIN 2.0e-5f

// Launder a wave-uniform value through ds_swizzle (identity for uniform
// input) so the compiler cannot prove uniformity and must use the VECTOR
// memory path (global_load_dwordx4, vmcnt-pipelined) instead of serialized
// s_load chains through the tiny scalar cache. Value is bit-identical.
__device__ __forceinline__ int launder_uniform(int v) {
    return __builtin_amdgcn_ds_swizzle(v, 0x1F);  // src lane = lane&31; v uniform
}

// ---------------------------------------------------------------------------
// Kernel 1: wsq[k] = numpy-emulated fp32 sum(w_k^2)  (+ zero the suspect ctr).
// [unchanged — proven]
// ---------------------------------------------------------------------------
__global__ __launch_bounds__(256)
void vq_wsq_kernel(const float* __restrict__ w, float* __restrict__ wsq,
                   int* __restrict__ scount, int K) {
    if (blockIdx.x == 0 && threadIdx.x == 0) scount[0] = 0;
    int k = blockIdx.x * 256 + threadIdx.x;
    if (k >= K) return;
    const float* wr = w + (size_t)k * EMB_D;
    float r[8];
#pragma unroll
    for (int j = 0; j < 8; ++j) r[j] = __fmul_rn(wr[j], wr[j]);
#pragma unroll
    for (int t = 1; t < 8; ++t)
#pragma unroll
        for (int j = 0; j < 8; ++j)
            r[j] = __fadd_rn(r[j], __fmul_rn(wr[t * 8 + j], wr[t * 8 + j]));
    float a = __fadd_rn(__fadd_rn(r[0], r[1]), __fadd_rn(r[2], r[3]));
    float b = __fadd_rn(__fadd_rn(r[4], r[5]), __fadd_rn(r[6], r[7]));
    wsq[k] = __fadd_rn(a, b);
}

// ---------------------------------------------------------------------------
// Kernel 2: fp32 SCREEN — round-5 proven logic; ONLY diff: k laundered to
// the vector-load path; launch bounds 4->3 waves/EU so load pipelining
// doesn't spill under the 128-VGPR cap.
// ---------------------------------------------------------------------------
__global__ __launch_bounds__(256, 3)
void vq_screen_kernel(const float* __restrict__ x, const float* __restrict__ w,
                      const float* __restrict__ wsq, int* __restrict__ fidx,
                      int* __restrict__ slist, int* __restrict__ scount,
                      int K, int N) {
    const int tid  = threadIdx.x;
    const int lane = tid & 63;
    const int wave = tid >> 6;
    const int row  = blockIdx.x * 64 + lane;

    const float4* xrow4 = (const float4*)(x + (size_t)row * EMB_D);
    float xr[EMB_D];
#pragma unroll
    for (int i = 0; i < EMB_D / 4; ++i) {
        float4 v = xrow4[i];
        xr[4 * i + 0] = v.x; xr[4 * i + 1] = v.y;
        xr[4 * i + 2] = v.z; xr[4 * i + 3] = v.w;
    }

    const int kchunk = K >> 2;
    const int kbase  = __builtin_amdgcn_readfirstlane(wave * kchunk);

    float s1 = INFINITY, s2 = INFINITY;
    int   k1 = kbase;
    for (int j = 0; j < kchunk; ++j) {
        const int k  = kbase + j;
        const int kv = launder_uniform(k);          // same value, VGPR-resident
        const float4* wr4 = (const float4*)(w + (size_t)kv * EMB_D);
        float a0 = 0.f, a1 = 0.f, a2 = 0.f, a3 = 0.f;
#pragma unroll
        for (int i = 0; i < EMB_D / 4; ++i) {
            float4 v = wr4[i];
            a0 = fmaf(xr[4 * i + 0], v.x, a0);
            a1 = fmaf(xr[4 * i + 1], v.y, a1);
            a2 = fmaf(xr[4 * i + 2], v.z, a2);
            a3 = fmaf(xr[4 * i + 3], v.w, a3);
        }
        const float dot = (a0 + a1) + (a2 + a3);
        const float s   = fmaf(-2.0f, dot, wsq[k]);
        if (s < s1)      { s2 = s1; s1 = s; k1 = k; }  // strict <: first-min
        else if (s < s2) { s2 = s; }
    }

    __shared__ float L1[4][64], L2[4][64];
    __shared__ int   LI[4][64];
    L1[wave][lane] = s1; L2[wave][lane] = s2; LI[wave][lane] = k1;
    __syncthreads();
    if (wave == 0) {
        float g1 = L1[0][lane], g2 = L2[0][lane];
        int   gk = LI[0][lane];
#pragma unroll
        for (int c = 1; c < 4; ++c) {
            float a = L1[c][lane], b = L2[c][lane];
            int   ak = LI[c][lane];
            if (a < g1) { g2 = fminf(g1, b); g1 = a; gk = ak; }
            else        { g2 = fminf(g2, a); }
        }
        fidx[row] = gk;
        if (g2 - g1 <= MARGIN) {          // includes exact ties
            int p = atomicAdd(scount, 1);
            slist[p] = row;
        }
    }
}

// ---------------------------------------------------------------------------
// Kernel 3: exact RESCORE — round-5 proven structure/arithmetic; ONLY diff:
// k laundered to the vector-load path (w row loads become pipelined
// global_load_dwordx4 instead of ~2900-cycle serialized s_load misses).
// ---------------------------------------------------------------------------
__global__ __launch_bounds__(256, 2)
void vq_rescore_kernel(const float* __restrict__ x, const float* __restrict__ w,
                       const float* __restrict__ wsq, int* __restrict__ fidx,
                       const int* __restrict__ slist,
                       const int* __restrict__ scount, int K, int N) {
    const int tid  = threadIdx.x;
    const int lane = tid & 63;
    const int wave = tid >> 6;
    const int cnt  = scount[0];

    __shared__ float lbest[4][64];
    __shared__ int   lidx[4][64];

    for (int tile = blockIdx.x; tile * 64 < cnt; tile += gridDim.x) {
        const int  li    = tile * 64 + lane;
        const bool valid = li < cnt;
        const int  row   = valid ? slist[li] : 0;

        const float4* xrow4 = (const float4*)(x + (size_t)row * EMB_D);
        float xr[EMB_D];
#pragma unroll
        for (int i = 0; i < EMB_D / 4; ++i) {
            float4 v = xrow4[i];
            xr[4 * i + 0] = v.x; xr[4 * i + 1] = v.y;
            xr[4 * i + 2] = v.z; xr[4 * i + 3] = v.w;
        }
        // numpy-emulated fp32 x_sq
        float r[8];
#pragma unroll
        for (int j = 0; j < 8; ++j) r[j] = __fmul_rn(xr[j], xr[j]);
#pragma unroll
        for (int t = 1; t < 8; ++t)
#pragma unroll
            for (int j = 0; j < 8; ++j)
                r[j] = __fadd_rn(r[j], __fmul_rn(xr[t * 8 + j], xr[t * 8 + j]));
        const float xsq = __fadd_rn(
            __fadd_rn(__fadd_rn(r[0], r[1]), __fadd_rn(r[2], r[3])),
            __fadd_rn(__fadd_rn(r[4], r[5]), __fadd_rn(r[6], r[7])));

        const int kchunk = K >> 2;
        const int kbase  = __builtin_amdgcn_readfirstlane(wave * kchunk);
        float best = INFINITY;
        int   bidx = 0;
        for (int j = 0; j < kchunk; ++j) {
            const int k  = kbase + j;
            const int kv = launder_uniform(k);      // same value, vector path
            const float4* wr4 = (const float4*)(w + (size_t)kv * EMB_D);
            double a0 = 0.0, a1 = 0.0, a2 = 0.0, a3 = 0.0;
#pragma unroll
            for (int i = 0; i < EMB_D / 4; ++i) {
                float4 v = wr4[i];
                a0 = fma((double)xr[4 * i + 0], (double)v.x, a0);
                a1 = fma((double)xr[4 * i + 1], (double)v.y, a1);
                a2 = fma((double)xr[4 * i + 2], (double)v.z, a2);
                a3 = fma((double)xr[4 * i + 3], (double)v.w, a3);
            }
            const float mf = (float)((a0 + a1) + (a2 + a3));
            const float t2 = __fsub_rn(xsq, __fmul_rn(2.0f, mf));
            const float sc = __fadd_rn(t2, wsq[k]);
            if (sc < best) { best = sc; bidx = k; }
        }

        lbest[wave][lane] = best;
        lidx[wave][lane]  = bidx;
        __syncthreads();
        if (wave == 0 && valid) {
            float b  = lbest[0][lane];
            int   bi = lidx[0][lane];
#pragma unroll
            for (int c = 1; c < 4; ++c) {
                float v = lbest[c][lane];
                if (v < b) { b = v; bi = lidx[c][lane]; }
            }
            fidx[row] = bi;
        }
        __syncthreads();   // protect LDS reuse next tile
    }
}

// ---------------------------------------------------------------------------
// Kernel 4: gather/write quantized + indices + per-block loss partials.
// [unchanged — proven]
// ---------------------------------------------------------------------------
__global__ __launch_bounds__(256)
void vq_gather_kernel(const float* __restrict__ x, const float* __restrict__ w,
                      const int* __restrict__ fidx, float* __restrict__ out,
                      float* __restrict__ blockloss, int N) {
    const int tid  = threadIdx.x;
    const int lane = tid & 63;
    const int wave = tid >> 6;
    __shared__ int kf[64];
    if (tid < 64) {
        int row = blockIdx.x * 64 + tid;
        int k = fidx[row];
        kf[tid] = k;
        out[(size_t)N * EMB_D + row] = (float)k;   // indices chunk as f32
    }
    __syncthreads();

    float lpart = 0.f;
#pragma unroll
    for (int rep = 0; rep < 4; ++rep) {
        int f4   = rep * 256 + tid;
        int rr   = f4 >> 4;
        int c    = f4 & 15;
        int k    = kf[rr];
        int grow = blockIdx.x * 64 + rr;
        float4 wv = ((const float4*)(w + (size_t)k * EMB_D))[c];
        float4 xq = ((const float4*)(x + (size_t)grow * EMB_D))[c];
        ((float4*)out)[(size_t)grow * (EMB_D / 4) + c] = wv;
        float dx = wv.x - xq.x, dy = wv.y - xq.y;
        float dz = wv.z - xq.z, dw = wv.w - xq.w;
        lpart += dx * dx + dy * dy + dz * dz + dw * dw;
    }
#pragma unroll
    for (int off = 32; off > 0; off >>= 1) lpart += __shfl_down(lpart, off);
    __shared__ float lred[4];
    if (lane == 0) lred[wave] = lpart;
    __syncthreads();
    if (tid == 0)
        blockloss[blockIdx.x] = (lred[0] + lred[1]) + (lred[2] + lred[3]);
}

// ---------------------------------------------------------------------------
// Kernel 5: loss = 1.25 * mean((q - x)^2)   [unchanged]
// ---------------------------------------------------------------------------
__global__ __launch_bounds__(256)
void vq_loss_kernel(const float* __restrict__ part, int nb,
                    float* __restrict__ out_loss, float scale) {
    float s = 0.f;
    for (int i = threadIdx.x; i < nb; i += 256) s += part[i];
#pragma unroll
    for (int off = 32; off > 0; off >>= 1) s += __shfl_down(s, off);
    __shared__ float red[4];
    int lane = threadIdx.x & 63, wave = threadIdx.x >> 6;
    if (lane == 0) red[wave] = s;
    __syncthreads();
    if (threadIdx.x == 0)
        out_loss[0] = ((red[0] + red[1]) + (red[2] + red[3])) * scale;
}

extern "C" void kernel_launch(void* const* d_in, const int* in_sizes, int n_in,
                              void* d_out, int out_size, void* d_ws, size_t ws_size,
                              hipStream_t stream) {
    const float* x = (const float*)d_in[0];
    const float* w = (const float*)d_in[1];
    float* out = (float*)d_out;
    const int xsz = in_sizes[0];   // N * D
    const int wsz = in_sizes[1];   // K * D
    const int N   = xsz / EMB_D;   // 65536
    const int K   = wsz / EMB_D;   // 1024
    const int NB  = N / 64;        // 1024

    // ws layout: [scount:64 int][slist:N int][fidx:N int][wsq:K f][blockloss:NB f]
    int*   scount    = (int*)d_ws;
    int*   slist     = scount + 64;
    int*   fidx      = slist + N;
    float* wsq       = (float*)(fidx + N);
    float* blockloss = wsq + K;

    vq_wsq_kernel<<<(K + 255) / 256, 256, 0, stream>>>(w, wsq, scount, K);
    vq_screen_kernel<<<NB, 256, 0, stream>>>(x, w, wsq, fidx, slist, scount, K, N);
    vq_rescore_kernel<<<256, 256, 0, stream>>>(x, w, wsq, fidx, slist, scount, K, N);
    vq_gather_kernel<<<NB, 256, 0, stream>>>(x, w, fidx, out, blockloss, N);
    vq_loss_kernel<<<1, 256, 0, stream>>>(blockloss, NB,
                                          out + (size_t)N * EMB_D + N,
                                          1.25f / (float)xsz);
}

// Round 7
// 603.924 us; speedup vs baseline: 1.1966x; 1.1966x over previous
//
#include <hip/hip_runtime.h>
#include <math.h>

#define EMB_D 64
#define MARGIN 2.0e-5f

// ---------------------------------------------------------------------------
// Kernel 1: wsq[k] = numpy-emulated fp32 sum(w_k^2)  (+ zero the suspect ctr).
// [unchanged — proven]
// ---------------------------------------------------------------------------
__global__ __launch_bounds__(256)
void vq_wsq_kernel(const float* __restrict__ w, float* __restrict__ wsq,
                   int* __restrict__ scount, int K) {
    if (blockIdx.x == 0 && threadIdx.x == 0) scount[0] = 0;
    int k = blockIdx.x * 256 + threadIdx.x;
    if (k >= K) return;
    const float* wr = w + (size_t)k * EMB_D;
    float r[8];
#pragma unroll
    for (int j = 0; j < 8; ++j) r[j] = __fmul_rn(wr[j], wr[j]);
#pragma unroll
    for (int t = 1; t < 8; ++t)
#pragma unroll
        for (int j = 0; j < 8; ++j)
            r[j] = __fadd_rn(r[j], __fmul_rn(wr[t * 8 + j], wr[t * 8 + j]));
    float a = __fadd_rn(__fadd_rn(r[0], r[1]), __fadd_rn(r[2], r[3]));
    float b = __fadd_rn(__fadd_rn(r[4], r[5]), __fadd_rn(r[6], r[7]));
    wsq[k] = __fadd_rn(a, b);
}

// ---------------------------------------------------------------------------
// Kernel 2: fp32 SCREEN — proven r5 s_load structure, now TWO rows per lane
// (block covers 128 rows) so each wave-uniform s_load batch of the w row
// feeds 128 FMAs instead of 64, hiding the scalar-miss latency.
// Per-row arithmetic, top-2 tracking, and tie-breaks identical to r5.
// ---------------------------------------------------------------------------
__global__ __launch_bounds__(256, 3)
void vq_screen_kernel(const float* __restrict__ x, const float* __restrict__ w,
                      const float* __restrict__ wsq, int* __restrict__ fidx,
                      int* __restrict__ slist, int* __restrict__ scount,
                      int K, int N) {
    const int tid  = threadIdx.x;
    const int lane = tid & 63;
    const int wave = tid >> 6;
    const int rowA = blockIdx.x * 128 + lane;
    const int rowB = rowA + 64;

    float xa[EMB_D], xb[EMB_D];
    {
        const float4* pa = (const float4*)(x + (size_t)rowA * EMB_D);
        const float4* pb = (const float4*)(x + (size_t)rowB * EMB_D);
#pragma unroll
        for (int i = 0; i < EMB_D / 4; ++i) {
            float4 va = pa[i], vb = pb[i];
            xa[4 * i + 0] = va.x; xa[4 * i + 1] = va.y;
            xa[4 * i + 2] = va.z; xa[4 * i + 3] = va.w;
            xb[4 * i + 0] = vb.x; xb[4 * i + 1] = vb.y;
            xb[4 * i + 2] = vb.z; xb[4 * i + 3] = vb.w;
        }
    }

    const int kchunk = K >> 2;
    const int kbase  = __builtin_amdgcn_readfirstlane(wave * kchunk);

    float s1a = INFINITY, s2a = INFINITY, s1b = INFINITY, s2b = INFINITY;
    int   k1a = kbase, k1b = kbase;
    for (int j = 0; j < kchunk; ++j) {
        const int k = kbase + j;                    // wave-uniform -> s_load
        const float* wr = w + (size_t)k * EMB_D;
        float a0 = 0.f, a1 = 0.f, a2 = 0.f, a3 = 0.f;
        float b0 = 0.f, b1 = 0.f, b2 = 0.f, b3 = 0.f;
#pragma unroll
        for (int i = 0; i < EMB_D; i += 4) {
            float w0 = wr[i + 0], w1 = wr[i + 1], w2 = wr[i + 2], w3 = wr[i + 3];
            a0 = fmaf(xa[i + 0], w0, a0);
            a1 = fmaf(xa[i + 1], w1, a1);
            a2 = fmaf(xa[i + 2], w2, a2);
            a3 = fmaf(xa[i + 3], w3, a3);
            b0 = fmaf(xb[i + 0], w0, b0);
            b1 = fmaf(xb[i + 1], w1, b1);
            b2 = fmaf(xb[i + 2], w2, b2);
            b3 = fmaf(xb[i + 3], w3, b3);
        }
        const float wk = wsq[k];
        const float sa = fmaf(-2.0f, (a0 + a1) + (a2 + a3), wk);
        const float sb = fmaf(-2.0f, (b0 + b1) + (b2 + b3), wk);
        if (sa < s1a)      { s2a = s1a; s1a = sa; k1a = k; }  // strict <
        else if (sa < s2a) { s2a = sa; }
        if (sb < s1b)      { s2b = s1b; s1b = sb; k1b = k; }
        else if (sb < s2b) { s2b = sb; }
    }

    __shared__ float L1[2][4][64], L2[2][4][64];
    __shared__ int   LI[2][4][64];
    L1[0][wave][lane] = s1a; L2[0][wave][lane] = s2a; LI[0][wave][lane] = k1a;
    L1[1][wave][lane] = s1b; L2[1][wave][lane] = s2b; LI[1][wave][lane] = k1b;
    __syncthreads();
    if (wave == 0) {
#pragma unroll
        for (int rsel = 0; rsel < 2; ++rsel) {
            float g1 = L1[rsel][0][lane], g2 = L2[rsel][0][lane];
            int   gk = LI[rsel][0][lane];
#pragma unroll
            for (int c = 1; c < 4; ++c) {
                float a = L1[rsel][c][lane], b = L2[rsel][c][lane];
                int   ak = LI[rsel][c][lane];
                if (a < g1) { g2 = fminf(g1, b); g1 = a; gk = ak; }
                else        { g2 = fminf(g2, a); }
            }
            const int row = rsel == 0 ? rowA : rowB;
            fidx[row] = gk;
            if (g2 - g1 <= MARGIN) {          // includes exact ties
                int p = atomicAdd(scount, 1);
                slist[p] = row;
            }
        }
    }
}

// ---------------------------------------------------------------------------
// Kernel 3: exact RESCORE — one block per suspect row; LANE = CODEWORD.
// Lane l of wave v scores k = v*(K/4) + t*64 + l, t=0..3, via per-lane
// pipelined float4 vector loads of its own w row (no scalar path, no
// dependent address chain). f64 dot -> f32 cast -> numpy rounding chain
// copied verbatim from the proven kernel. Argmin = lexicographic (score,k)
// min — associative and order-independent, equals np.argmin first-min.
// ---------------------------------------------------------------------------
__global__ __launch_bounds__(256, 4)
void vq_rescore_kernel(const float* __restrict__ x, const float* __restrict__ w,
                       const float* __restrict__ wsq, int* __restrict__ fidx,
                       const int* __restrict__ slist,
                       const int* __restrict__ scount, int K) {
    const int tid  = threadIdx.x;
    const int lane = tid & 63;
    const int wave = tid >> 6;
    const int cnt  = scount[0];

    __shared__ float ls[256];
    __shared__ int   lk[256];

    for (int si = blockIdx.x; si < cnt; si += gridDim.x) {
        const int row = slist[si];

        // broadcast-load x row
        const float4* xrow4 = (const float4*)(x + (size_t)row * EMB_D);
        float xr[EMB_D];
#pragma unroll
        for (int i = 0; i < EMB_D / 4; ++i) {
            float4 v = xrow4[i];
            xr[4 * i + 0] = v.x; xr[4 * i + 1] = v.y;
            xr[4 * i + 2] = v.z; xr[4 * i + 3] = v.w;
        }
        // numpy-emulated fp32 x_sq [proven chain]
        float r[8];
#pragma unroll
        for (int j = 0; j < 8; ++j) r[j] = __fmul_rn(xr[j], xr[j]);
#pragma unroll
        for (int t = 1; t < 8; ++t)
#pragma unroll
            for (int j = 0; j < 8; ++j)
                r[j] = __fadd_rn(r[j], __fmul_rn(xr[t * 8 + j], xr[t * 8 + j]));
        const float xsq = __fadd_rn(
            __fadd_rn(__fadd_rn(r[0], r[1]), __fadd_rn(r[2], r[3])),
            __fadd_rn(__fadd_rn(r[4], r[5]), __fadd_rn(r[6], r[7])));

        float bs = INFINITY;
        int   bk = K;
#pragma unroll
        for (int t = 0; t < 4; ++t) {
            const int k = wave * (K >> 2) + t * 64 + lane;   // per-lane k
            const float4* wr4 = (const float4*)(w + (size_t)k * EMB_D);
            double a0 = 0.0, a1 = 0.0, a2 = 0.0, a3 = 0.0;
#pragma unroll
            for (int i = 0; i < EMB_D / 4; ++i) {
                float4 v = wr4[i];
                a0 = fma((double)xr[4 * i + 0], (double)v.x, a0);
                a1 = fma((double)xr[4 * i + 1], (double)v.y, a1);
                a2 = fma((double)xr[4 * i + 2], (double)v.z, a2);
                a3 = fma((double)xr[4 * i + 3], (double)v.w, a3);
            }
            const float mf = (float)((a0 + a1) + (a2 + a3));
            const float t2 = __fsub_rn(xsq, __fmul_rn(2.0f, mf));
            const float sc = __fadd_rn(t2, wsq[k]);
            if (sc < bs || (sc == bs && k < bk)) { bs = sc; bk = k; }  // lex-min
        }

        ls[tid] = bs; lk[tid] = bk;
        __syncthreads();
        if (wave == 0) {
            float gs = ls[lane];
            int   gk = lk[lane];
#pragma unroll
            for (int c = 1; c < 4; ++c) {
                float os = ls[c * 64 + lane];
                int   ok = lk[c * 64 + lane];
                if (os < gs || (os == gs && ok < gk)) { gs = os; gk = ok; }
            }
#pragma unroll
            for (int off = 32; off > 0; off >>= 1) {
                float os = __shfl_down(gs, off);
                int   ok = __shfl_down(gk, off);
                if (os < gs || (os == gs && ok < gk)) { gs = os; gk = ok; }
            }
            if (lane == 0) fidx[row] = gk;
        }
        __syncthreads();   // protect LDS reuse next suspect row
    }
}

// ---------------------------------------------------------------------------
// Kernel 4: gather/write quantized + indices + per-block loss partials.
// [unchanged — proven]
// ---------------------------------------------------------------------------
__global__ __launch_bounds__(256)
void vq_gather_kernel(const float* __restrict__ x, const float* __restrict__ w,
                      const int* __restrict__ fidx, float* __restrict__ out,
                      float* __restrict__ blockloss, int N) {
    const int tid  = threadIdx.x;
    const int lane = tid & 63;
    const int wave = tid >> 6;
    __shared__ int kf[64];
    if (tid < 64) {
        int row = blockIdx.x * 64 + tid;
        int k = fidx[row];
        kf[tid] = k;
        out[(size_t)N * EMB_D + row] = (float)k;   // indices chunk as f32
    }
    __syncthreads();

    float lpart = 0.f;
#pragma unroll
    for (int rep = 0; rep < 4; ++rep) {
        int f4   = rep * 256 + tid;
        int rr   = f4 >> 4;
        int c    = f4 & 15;
        int k    = kf[rr];
        int grow = blockIdx.x * 64 + rr;
        float4 wv = ((const float4*)(w + (size_t)k * EMB_D))[c];
        float4 xq = ((const float4*)(x + (size_t)grow * EMB_D))[c];
        ((float4*)out)[(size_t)grow * (EMB_D / 4) + c] = wv;
        float dx = wv.x - xq.x, dy = wv.y - xq.y;
        float dz = wv.z - xq.z, dw = wv.w - xq.w;
        lpart += dx * dx + dy * dy + dz * dz + dw * dw;
    }
#pragma unroll
    for (int off = 32; off > 0; off >>= 1) lpart += __shfl_down(lpart, off);
    __shared__ float lred[4];
    if (lane == 0) lred[wave] = lpart;
    __syncthreads();
    if (tid == 0)
        blockloss[blockIdx.x] = (lred[0] + lred[1]) + (lred[2] + lred[3]);
}

// ---------------------------------------------------------------------------
// Kernel 5: loss = 1.25 * mean((q - x)^2)   [unchanged]
// ---------------------------------------------------------------------------
__global__ __launch_bounds__(256)
void vq_loss_kernel(const float* __restrict__ part, int nb,
                    float* __restrict__ out_loss, float scale) {
    float s = 0.f;
    for (int i = threadIdx.x; i < nb; i += 256) s += part[i];
#pragma unroll
    for (int off = 32; off > 0; off >>= 1) s += __shfl_down(s, off);
    __shared__ float red[4];
    int lane = threadIdx.x & 63, wave = threadIdx.x >> 6;
    if (lane == 0) red[wave] = s;
    __syncthreads();
    if (threadIdx.x == 0)
        out_loss[0] = ((red[0] + red[1]) + (red[2] + red[3])) * scale;
}

extern "C" void kernel_launch(void* const* d_in, const int* in_sizes, int n_in,
                              void* d_out, int out_size, void* d_ws, size_t ws_size,
                              hipStream_t stream) {
    const float* x = (const float*)d_in[0];
    const float* w = (const float*)d_in[1];
    float* out = (float*)d_out;
    const int xsz = in_sizes[0];   // N * D
    const int wsz = in_sizes[1];   // K * D
    const int N   = xsz / EMB_D;   // 65536
    const int K   = wsz / EMB_D;   // 1024
    const int NB  = N / 64;        // 1024

    // ws layout: [scount:64 int][slist:N int][fidx:N int][wsq:K f][blockloss:NB f]
    int*   scount    = (int*)d_ws;
    int*   slist     = scount + 64;
    int*   fidx      = slist + N;
    float* wsq       = (float*)(fidx + N);
    float* blockloss = wsq + K;

    vq_wsq_kernel<<<(K + 255) / 256, 256, 0, stream>>>(w, wsq, scount, K);
    vq_screen_kernel<<<N / 128, 256, 0, stream>>>(x, w, wsq, fidx, slist, scount, K, N);
    vq_rescore_kernel<<<NB, 256, 0, stream>>>(x, w, wsq, fidx, slist, scount, K);
    vq_gather_kernel<<<NB, 256, 0, stream>>>(x, w, fidx, out, blockloss, N);
    vq_loss_kernel<<<1, 256, 0, stream>>>(blockloss, NB,
                                          out + (size_t)N * EMB_D + N,
                                          1.25f / (float)xsz);
}

// Round 8
// 392.299 us; speedup vs baseline: 1.8422x; 1.5394x over previous
//
#include <hip/hip_runtime.h>
#include <math.h>

#define EMB_D 64
#define MARGIN 2.0e-5f

// ---------------------------------------------------------------------------
// Kernel 1: wsq[k] = numpy-emulated fp32 sum(w_k^2).  [proven]
// numpy pairwise_sum n=64: 8 accumulators r[j]=sum_t a[j+8t], then
// ((r0+r1)+(r2+r3)) + ((r4+r5)+(r6+r7)).
// ---------------------------------------------------------------------------
__global__ __launch_bounds__(256)
void vq_wsq_kernel(const float* __restrict__ w, float* __restrict__ wsq, int K) {
    int k = blockIdx.x * 256 + threadIdx.x;
    if (k >= K) return;
    const float* wr = w + (size_t)k * EMB_D;
    float r[8];
#pragma unroll
    for (int j = 0; j < 8; ++j) r[j] = __fmul_rn(wr[j], wr[j]);
#pragma unroll
    for (int t = 1; t < 8; ++t)
#pragma unroll
        for (int j = 0; j < 8; ++j)
            r[j] = __fadd_rn(r[j], __fmul_rn(wr[t * 8 + j], wr[t * 8 + j]));
    float a = __fadd_rn(__fadd_rn(r[0], r[1]), __fadd_rn(r[2], r[3]));
    float b = __fadd_rn(__fadd_rn(r[4], r[5]), __fadd_rn(r[6], r[7]));
    wsq[k] = __fadd_rn(a, b);
}

// ---------------------------------------------------------------------------
// Kernel 2: SCREEN (r5-proven s_load structure, 1 row/lane) with FUSED exact
// rescore of this block's suspect rows (r7-proven arithmetic). No slist, no
// scount, no separate rescore dispatch.
// ---------------------------------------------------------------------------
__global__ __launch_bounds__(256, 4)
void vq_screen_kernel(const float* __restrict__ x, const float* __restrict__ w,
                      const float* __restrict__ wsq, int* __restrict__ fidx,
                      int K, int N) {
    const int tid  = threadIdx.x;
    const int lane = tid & 63;
    const int wave = tid >> 6;
    const int row  = blockIdx.x * 64 + lane;

    // ---- screen phase: r5 verbatim ----
    {
        const float4* xrow4 = (const float4*)(x + (size_t)row * EMB_D);
        float xr[EMB_D];
#pragma unroll
        for (int i = 0; i < EMB_D / 4; ++i) {
            float4 v = xrow4[i];
            xr[4 * i + 0] = v.x; xr[4 * i + 1] = v.y;
            xr[4 * i + 2] = v.z; xr[4 * i + 3] = v.w;
        }

        const int kchunk = K >> 2;
        const int kbase  = __builtin_amdgcn_readfirstlane(wave * kchunk);

        float s1 = INFINITY, s2 = INFINITY;
        int   k1 = kbase;
        for (int j = 0; j < kchunk; ++j) {
            const int k = kbase + j;                 // wave-uniform -> s_load
            const float* wr = w + (size_t)k * EMB_D;
            float a0 = 0.f, a1 = 0.f, a2 = 0.f, a3 = 0.f;
#pragma unroll
            for (int i = 0; i < EMB_D; i += 4) {
                a0 = fmaf(xr[i + 0], wr[i + 0], a0);
                a1 = fmaf(xr[i + 1], wr[i + 1], a1);
                a2 = fmaf(xr[i + 2], wr[i + 2], a2);
                a3 = fmaf(xr[i + 3], wr[i + 3], a3);
            }
            const float dot = (a0 + a1) + (a2 + a3);
            const float s   = fmaf(-2.0f, dot, wsq[k]);
            if (s < s1)      { s2 = s1; s1 = s; k1 = k; }  // strict <: first-min
            else if (s < s2) { s2 = s; }
        }

        __shared__ float L1[4][64], L2[4][64];
        __shared__ int   LI[4][64];
        L1[wave][lane] = s1; L2[wave][lane] = s2; LI[wave][lane] = k1;
        __syncthreads();
        __shared__ int sus[64];
        if (wave == 0) {
            float g1 = L1[0][lane], g2 = L2[0][lane];
            int   gk = LI[0][lane];
#pragma unroll
            for (int c = 1; c < 4; ++c) {
                float a = L1[c][lane], b = L2[c][lane];
                int   ak = LI[c][lane];
                if (a < g1) { g2 = fminf(g1, b); g1 = a; gk = ak; }
                else        { g2 = fminf(g2, a); }
            }
            fidx[row] = gk;
            sus[lane] = (g2 - g1 <= MARGIN) ? 1 : 0;   // incl. exact ties
        }
        __syncthreads();

        // ---- fused rescore phase: r7 arithmetic verbatim, one suspect row
        //      at a time, all 256 threads cooperating ----
        __shared__ float ls[256];
        __shared__ int   lk[256];
        for (int i = 0; i < 64; ++i) {
            if (sus[i] == 0) continue;               // block-uniform branch
            const int rrow = blockIdx.x * 64 + i;

            // broadcast-load suspect row
            const float4* xq4 = (const float4*)(x + (size_t)rrow * EMB_D);
            float xr2[EMB_D];
#pragma unroll
            for (int q = 0; q < EMB_D / 4; ++q) {
                float4 v = xq4[q];
                xr2[4 * q + 0] = v.x; xr2[4 * q + 1] = v.y;
                xr2[4 * q + 2] = v.z; xr2[4 * q + 3] = v.w;
            }
            // numpy-emulated fp32 x_sq [proven chain]
            float rr[8];
#pragma unroll
            for (int j = 0; j < 8; ++j) rr[j] = __fmul_rn(xr2[j], xr2[j]);
#pragma unroll
            for (int t = 1; t < 8; ++t)
#pragma unroll
                for (int j = 0; j < 8; ++j)
                    rr[j] = __fadd_rn(rr[j],
                                      __fmul_rn(xr2[t * 8 + j], xr2[t * 8 + j]));
            const float xsq2 = __fadd_rn(
                __fadd_rn(__fadd_rn(rr[0], rr[1]), __fadd_rn(rr[2], rr[3])),
                __fadd_rn(__fadd_rn(rr[4], rr[5]), __fadd_rn(rr[6], rr[7])));

            float bs = INFINITY;
            int   bk = K;
#pragma unroll
            for (int t = 0; t < 4; ++t) {
                const int k = wave * (K >> 2) + t * 64 + lane;  // per-lane k
                const float4* wr4 = (const float4*)(w + (size_t)k * EMB_D);
                double a0 = 0.0, a1 = 0.0, a2 = 0.0, a3 = 0.0;
#pragma unroll
                for (int q = 0; q < EMB_D / 4; ++q) {
                    float4 v = wr4[q];
                    a0 = fma((double)xr2[4 * q + 0], (double)v.x, a0);
                    a1 = fma((double)xr2[4 * q + 1], (double)v.y, a1);
                    a2 = fma((double)xr2[4 * q + 2], (double)v.z, a2);
                    a3 = fma((double)xr2[4 * q + 3], (double)v.w, a3);
                }
                const float mf = (float)((a0 + a1) + (a2 + a3));
                const float t2 = __fsub_rn(xsq2, __fmul_rn(2.0f, mf));
                const float sc = __fadd_rn(t2, wsq[k]);
                if (sc < bs || (sc == bs && k < bk)) { bs = sc; bk = k; }
            }

            ls[tid] = bs; lk[tid] = bk;
            __syncthreads();
            if (wave == 0) {
                float gs = ls[lane];
                int   gk2 = lk[lane];
#pragma unroll
                for (int c = 1; c < 4; ++c) {
                    float os = ls[c * 64 + lane];
                    int   ok = lk[c * 64 + lane];
                    if (os < gs || (os == gs && ok < gk2)) { gs = os; gk2 = ok; }
                }
#pragma unroll
                for (int off = 32; off > 0; off >>= 1) {
                    float os = __shfl_down(gs, off);
                    int   ok = __shfl_down(gk2, off);
                    if (os < gs || (os == gs && ok < gk2)) { gs = os; gk2 = ok; }
                }
                if (lane == 0) fidx[rrow] = gk2;
            }
            __syncthreads();   // protect ls/lk reuse for next suspect
        }
    }
}

// ---------------------------------------------------------------------------
// Kernel 3: gather/write quantized + indices + per-block loss partials.
// [unchanged — proven]
// ---------------------------------------------------------------------------
__global__ __launch_bounds__(256)
void vq_gather_kernel(const float* __restrict__ x, const float* __restrict__ w,
                      const int* __restrict__ fidx, float* __restrict__ out,
                      float* __restrict__ blockloss, int N) {
    const int tid  = threadIdx.x;
    const int lane = tid & 63;
    const int wave = tid >> 6;
    __shared__ int kf[64];
    if (tid < 64) {
        int row = blockIdx.x * 64 + tid;
        int k = fidx[row];
        kf[tid] = k;
        out[(size_t)N * EMB_D + row] = (float)k;   // indices chunk as f32
    }
    __syncthreads();

    float lpart = 0.f;
#pragma unroll
    for (int rep = 0; rep < 4; ++rep) {
        int f4   = rep * 256 + tid;
        int rr   = f4 >> 4;
        int c    = f4 & 15;
        int k    = kf[rr];
        int grow = blockIdx.x * 64 + rr;
        float4 wv = ((const float4*)(w + (size_t)k * EMB_D))[c];
        float4 xq = ((const float4*)(x + (size_t)grow * EMB_D))[c];
        ((float4*)out)[(size_t)grow * (EMB_D / 4) + c] = wv;
        float dx = wv.x - xq.x, dy = wv.y - xq.y;
        float dz = wv.z - xq.z, dw = wv.w - xq.w;
        lpart += dx * dx + dy * dy + dz * dz + dw * dw;
    }
#pragma unroll
    for (int off = 32; off > 0; off >>= 1) lpart += __shfl_down(lpart, off);
    __shared__ float lred[4];
    if (lane == 0) lred[wave] = lpart;
    __syncthreads();
    if (tid == 0)
        blockloss[blockIdx.x] = (lred[0] + lred[1]) + (lred[2] + lred[3]);
}

// ---------------------------------------------------------------------------
// Kernel 4: loss = 1.25 * mean((q - x)^2)   [unchanged]
// ---------------------------------------------------------------------------
__global__ __launch_bounds__(256)
void vq_loss_kernel(const float* __restrict__ part, int nb,
                    float* __restrict__ out_loss, float scale) {
    float s = 0.f;
    for (int i = threadIdx.x; i < nb; i += 256) s += part[i];
#pragma unroll
    for (int off = 32; off > 0; off >>= 1) s += __shfl_down(s, off);
    __shared__ float red[4];
    int lane = threadIdx.x & 63, wave = threadIdx.x >> 6;
    if (lane == 0) red[wave] = s;
    __syncthreads();
    if (threadIdx.x == 0)
        out_loss[0] = ((red[0] + red[1]) + (red[2] + red[3])) * scale;
}

extern "C" void kernel_launch(void* const* d_in, const int* in_sizes, int n_in,
                              void* d_out, int out_size, void* d_ws, size_t ws_size,
                              hipStream_t stream) {
    const float* x = (const float*)d_in[0];
    const float* w = (const float*)d_in[1];
    float* out = (float*)d_out;
    const int xsz = in_sizes[0];   // N * D
    const int wsz = in_sizes[1];   // K * D
    const int N   = xsz / EMB_D;   // 65536
    const int K   = wsz / EMB_D;   // 1024
    const int NB  = N / 64;        // 1024

    // ws layout: [fidx: N int][wsq: K float][blockloss: NB float]
    int*   fidx      = (int*)d_ws;
    float* wsq       = (float*)(fidx + N);
    float* blockloss = wsq + K;

    vq_wsq_kernel<<<(K + 255) / 256, 256, 0, stream>>>(w, wsq, K);
    vq_screen_kernel<<<NB, 256, 0, stream>>>(x, w, wsq, fidx, K, N);
    vq_gather_kernel<<<NB, 256, 0, stream>>>(x, w, fidx, out, blockloss, N);
    vq_loss_kernel<<<1, 256, 0, stream>>>(blockloss, NB,
                                          out + (size_t)N * EMB_D + N,
                                          1.25f / (float)xsz);
}

// Round 9
// 307.513 us; speedup vs baseline: 2.3501x; 1.2757x over previous
//
#include <hip/hip_runtime.h>
#include <math.h>

#define EMB_D 64
#define MARGIN 6.0e-5f   // covers ref fp32-rounding band (~1.6e-5) + bf16-split screen err (~6e-6) with 2x slack

typedef float  f32x4  __attribute__((ext_vector_type(4)));
typedef short  bf16x8 __attribute__((ext_vector_type(8)));

// round-to-nearest-even f32 -> bf16 (finite inputs)
__device__ __forceinline__ unsigned short f2bf(float f) {
    unsigned int u = __float_as_uint(f);
    return (unsigned short)((u + 0x7FFFu + ((u >> 16) & 1u)) >> 16);
}
__device__ __forceinline__ float bf2f(unsigned short h) {
    return __uint_as_float(((unsigned int)h) << 16);
}

// ---------------------------------------------------------------------------
// Prep: split fp32 array into bf16 hi + lo (x - hi).  Also zeroes scount
// when zc != nullptr.
// ---------------------------------------------------------------------------
__global__ __launch_bounds__(256)
void vq_prep_kernel(const float* __restrict__ src, unsigned short* __restrict__ hi,
                    unsigned short* __restrict__ lo, int n4, int* zc) {
    if (zc && blockIdx.x == 0 && threadIdx.x == 0) zc[0] = 0;
    int i = blockIdx.x * 256 + threadIdx.x;
    if (i >= n4) return;
    float4 v = ((const float4*)src)[i];
    ushort4 h, l;
    h.x = f2bf(v.x); l.x = f2bf(v.x - bf2f(h.x));
    h.y = f2bf(v.y); l.y = f2bf(v.y - bf2f(h.y));
    h.z = f2bf(v.z); l.z = f2bf(v.z - bf2f(h.z));
    h.w = f2bf(v.w); l.w = f2bf(v.w - bf2f(h.w));
    ((ushort4*)hi)[i] = h;
    ((ushort4*)lo)[i] = l;
}

// ---------------------------------------------------------------------------
// Kernel 1: wsq[k] = numpy-emulated fp32 sum(w_k^2).  [proven]
// ---------------------------------------------------------------------------
__global__ __launch_bounds__(256)
void vq_wsq_kernel(const float* __restrict__ w, float* __restrict__ wsq, int K) {
    int k = blockIdx.x * 256 + threadIdx.x;
    if (k >= K) return;
    const float* wr = w + (size_t)k * EMB_D;
    float r[8];
#pragma unroll
    for (int j = 0; j < 8; ++j) r[j] = __fmul_rn(wr[j], wr[j]);
#pragma unroll
    for (int t = 1; t < 8; ++t)
#pragma unroll
        for (int j = 0; j < 8; ++j)
            r[j] = __fadd_rn(r[j], __fmul_rn(wr[t * 8 + j], wr[t * 8 + j]));
    float a = __fadd_rn(__fadd_rn(r[0], r[1]), __fadd_rn(r[2], r[3]));
    float b = __fadd_rn(__fadd_rn(r[4], r[5]), __fadd_rn(r[6], r[7]));
    wsq[k] = __fadd_rn(a, b);
}

// ---------------------------------------------------------------------------
// Kernel 2: MFMA SCREEN.  Per block: 64 rows (wave w owns 16 rows).
// dot = xhi*whi + xhi*wlo + xlo*whi via mfma_f32_16x16x32_bf16.
// Layouts (m89/m120-verified): A[m=lane&15][k=quad*8+j]; B[n=lane&15][k=...];
// C/D col=lane&15, row=quad*4+reg.  Top-2 per (row, col-residue) per lane,
// cross-residue merge in LDS.  Rows with g2-g1<=MARGIN -> suspect list
// (exact ties included), resolved by the exact rescore kernel.
// ---------------------------------------------------------------------------
__global__ __launch_bounds__(256, 4)
void vq_screen_kernel(const unsigned short* __restrict__ xhi,
                      const unsigned short* __restrict__ xlo,
                      const unsigned short* __restrict__ whi,
                      const unsigned short* __restrict__ wlo,
                      const float* __restrict__ wsq, int* __restrict__ fidx,
                      int* __restrict__ slist, int* __restrict__ scount,
                      int K, int N) {
    const int tid  = threadIdx.x;
    const int lane = tid & 63;
    const int wave = tid >> 6;
    const int quad = lane >> 4;
    const int c16  = lane & 15;
    const int rowbase = blockIdx.x * 64 + wave * 16;

    // A-frags: row = rowbase + c16, depth = chunk*32 + quad*8 + j
    const size_t arow = (size_t)(rowbase + c16) * EMB_D + quad * 8;
    const bf16x8 ahi0 = *(const bf16x8*)(xhi + arow);
    const bf16x8 ahi1 = *(const bf16x8*)(xhi + arow + 32);
    const bf16x8 alo0 = *(const bf16x8*)(xlo + arow);
    const bf16x8 alo1 = *(const bf16x8*)(xlo + arow + 32);

    float s1[4], s2[4];
    int   k1[4];
#pragma unroll
    for (int i = 0; i < 4; ++i) { s1[i] = INFINITY; s2[i] = INFINITY; k1[i] = 0; }

    const int ntile = K >> 4;
    for (int t = 0; t < ntile; ++t) {
        const size_t brow = (size_t)(t * 16 + c16) * EMB_D + quad * 8;
        const bf16x8 bhi0 = *(const bf16x8*)(whi + brow);
        const bf16x8 bhi1 = *(const bf16x8*)(whi + brow + 32);
        const bf16x8 blo0 = *(const bf16x8*)(wlo + brow);
        const bf16x8 blo1 = *(const bf16x8*)(wlo + brow + 32);
        f32x4 acc = {0.f, 0.f, 0.f, 0.f};
        acc = __builtin_amdgcn_mfma_f32_16x16x32_bf16(alo0, bhi0, acc, 0, 0, 0);
        acc = __builtin_amdgcn_mfma_f32_16x16x32_bf16(ahi0, blo0, acc, 0, 0, 0);
        acc = __builtin_amdgcn_mfma_f32_16x16x32_bf16(ahi0, bhi0, acc, 0, 0, 0);
        acc = __builtin_amdgcn_mfma_f32_16x16x32_bf16(alo1, bhi1, acc, 0, 0, 0);
        acc = __builtin_amdgcn_mfma_f32_16x16x32_bf16(ahi1, blo1, acc, 0, 0, 0);
        acc = __builtin_amdgcn_mfma_f32_16x16x32_bf16(ahi1, bhi1, acc, 0, 0, 0);

        const float wq = wsq[t * 16 + c16];
        const int   kk = t * 16 + c16;      // strictly increasing per lane
#pragma unroll
        for (int i = 0; i < 4; ++i) {
            const float s = fmaf(-2.0f, acc[i], wq);
            if (s < s1[i])      { s2[i] = s1[i]; s1[i] = s; k1[i] = kk; }
            else if (s < s2[i]) { s2[i] = s; }
        }
    }

    // cross-residue merge: lane holds rows quad*4+i, col residue c16
    __shared__ float M1[4][16][16], M2[4][16][16];
    __shared__ int   MK[4][16][16];
#pragma unroll
    for (int i = 0; i < 4; ++i) {
        const int r16 = quad * 4 + i;
        M1[wave][r16][c16] = s1[i];
        M2[wave][r16][c16] = s2[i];
        MK[wave][r16][c16] = k1[i];
    }
    __syncthreads();
    if (lane < 16) {
        float g1 = M1[wave][lane][0], g2 = M2[wave][lane][0];
        int   gk = MK[wave][lane][0];
#pragma unroll
        for (int c = 1; c < 16; ++c) {
            const float a1 = M1[wave][lane][c];
            const float a2 = M2[wave][lane][c];
            const int   ak = MK[wave][lane][c];
            if (a1 < g1) { g2 = fminf(g1, a2); g1 = a1; gk = ak; }
            else         { g2 = fminf(g2, a1); }
        }
        const int row = rowbase + lane;
        fidx[row] = gk;
        if (g2 - g1 <= MARGIN) {       // ambiguous at screen precision (incl. ties)
            int p = atomicAdd(scount, 1);
            slist[p] = row;
        }
    }
}

// ---------------------------------------------------------------------------
// Kernel 3: exact RESCORE (r8-proven arithmetic).  One block per suspect
// row, grid-stride.  x row in LDS (broadcast ds reads — no 64-float
// register array, no spill).  Per-lane k = wave*256 + t*64 + lane, per-lane
// vector loads of w.  f64 dot -> f32 -> numpy rounding chain; lex (score,k)
// min == np.argmin first-min.
// ---------------------------------------------------------------------------
__global__ __launch_bounds__(256, 4)
void vq_rescore_kernel(const float* __restrict__ x, const float* __restrict__ w,
                       const float* __restrict__ wsq, int* __restrict__ fidx,
                       const int* __restrict__ slist,
                       const int* __restrict__ scount, int K) {
    const int tid  = threadIdx.x;
    const int lane = tid & 63;
    const int wave = tid >> 6;
    const int cnt  = scount[0];

    __shared__ float4 xs4[16];
    __shared__ float  xsqs;
    __shared__ float  ls[256];
    __shared__ int    lk[256];

    for (int si = blockIdx.x; si < cnt; si += gridDim.x) {
        const int row = slist[si];
        if (tid < 16) xs4[tid] = ((const float4*)(x + (size_t)row * EMB_D))[tid];
        __syncthreads();
        if (tid == 0) {
            const float* xf = (const float*)xs4;
            float r[8];
#pragma unroll
            for (int j = 0; j < 8; ++j) r[j] = __fmul_rn(xf[j], xf[j]);
#pragma unroll
            for (int t = 1; t < 8; ++t)
#pragma unroll
                for (int j = 0; j < 8; ++j)
                    r[j] = __fadd_rn(r[j], __fmul_rn(xf[t * 8 + j], xf[t * 8 + j]));
            xsqs = __fadd_rn(
                __fadd_rn(__fadd_rn(r[0], r[1]), __fadd_rn(r[2], r[3])),
                __fadd_rn(__fadd_rn(r[4], r[5]), __fadd_rn(r[6], r[7])));
        }
        __syncthreads();
        const float xsq = xsqs;

        float bs = INFINITY;
        int   bk = K;
        for (int t = 0; t < 4; ++t) {
            const int k = wave * (K >> 2) + t * 64 + lane;   // per-lane k
            const float4* wr4 = (const float4*)(w + (size_t)k * EMB_D);
            double a0 = 0.0, a1 = 0.0, a2 = 0.0, a3 = 0.0;
#pragma unroll
            for (int q = 0; q < EMB_D / 4; ++q) {
                const float4 xv = xs4[q];      // LDS broadcast
                const float4 wv = wr4[q];
                a0 = fma((double)xv.x, (double)wv.x, a0);
                a1 = fma((double)xv.y, (double)wv.y, a1);
                a2 = fma((double)xv.z, (double)wv.z, a2);
                a3 = fma((double)xv.w, (double)wv.w, a3);
            }
            const float mf = (float)((a0 + a1) + (a2 + a3));
            const float t2 = __fsub_rn(xsq, __fmul_rn(2.0f, mf));
            const float sc = __fadd_rn(t2, wsq[k]);
            if (sc < bs || (sc == bs && k < bk)) { bs = sc; bk = k; }
        }

        ls[tid] = bs; lk[tid] = bk;
        __syncthreads();
        if (wave == 0) {
            float gs = ls[lane];
            int   gk = lk[lane];
#pragma unroll
            for (int c = 1; c < 4; ++c) {
                const float os = ls[c * 64 + lane];
                const int   ok = lk[c * 64 + lane];
                if (os < gs || (os == gs && ok < gk)) { gs = os; gk = ok; }
            }
#pragma unroll
            for (int off = 32; off > 0; off >>= 1) {
                const float os = __shfl_down(gs, off);
                const int   ok = __shfl_down(gk, off);
                if (os < gs || (os == gs && ok < gk)) { gs = os; gk = ok; }
            }
            if (lane == 0) fidx[row] = gk;
        }
        __syncthreads();
    }
}

// ---------------------------------------------------------------------------
// Kernel 4: gather/write quantized + indices + per-block loss partials.
// [unchanged — proven]
// ---------------------------------------------------------------------------
__global__ __launch_bounds__(256)
void vq_gather_kernel(const float* __restrict__ x, const float* __restrict__ w,
                      const int* __restrict__ fidx, float* __restrict__ out,
                      float* __restrict__ blockloss, int N) {
    const int tid  = threadIdx.x;
    const int lane = tid & 63;
    const int wave = tid >> 6;
    __shared__ int kf[64];
    if (tid < 64) {
        int row = blockIdx.x * 64 + tid;
        int k = fidx[row];
        kf[tid] = k;
        out[(size_t)N * EMB_D + row] = (float)k;   // indices chunk as f32
    }
    __syncthreads();

    float lpart = 0.f;
#pragma unroll
    for (int rep = 0; rep < 4; ++rep) {
        int f4   = rep * 256 + tid;
        int rr   = f4 >> 4;
        int c    = f4 & 15;
        int k    = kf[rr];
        int grow = blockIdx.x * 64 + rr;
        float4 wv = ((const float4*)(w + (size_t)k * EMB_D))[c];
        float4 xq = ((const float4*)(x + (size_t)grow * EMB_D))[c];
        ((float4*)out)[(size_t)grow * (EMB_D / 4) + c] = wv;
        float dx = wv.x - xq.x, dy = wv.y - xq.y;
        float dz = wv.z - xq.z, dw = wv.w - xq.w;
        lpart += dx * dx + dy * dy + dz * dz + dw * dw;
    }
#pragma unroll
    for (int off = 32; off > 0; off >>= 1) lpart += __shfl_down(lpart, off);
    __shared__ float lred[4];
    if (lane == 0) lred[wave] = lpart;
    __syncthreads();
    if (tid == 0)
        blockloss[blockIdx.x] = (lred[0] + lred[1]) + (lred[2] + lred[3]);
}

// ---------------------------------------------------------------------------
// Kernel 5: loss = 1.25 * mean((q - x)^2)   [unchanged — proven]
// ---------------------------------------------------------------------------
__global__ __launch_bounds__(256)
void vq_loss_kernel(const float* __restrict__ part, int nb,
                    float* __restrict__ out_loss, float scale) {
    float s = 0.f;
    for (int i = threadIdx.x; i < nb; i += 256) s += part[i];
#pragma unroll
    for (int off = 32; off > 0; off >>= 1) s += __shfl_down(s, off);
    __shared__ float red[4];
    int lane = threadIdx.x & 63, wave = threadIdx.x >> 6;
    if (lane == 0) red[wave] = s;
    __syncthreads();
    if (threadIdx.x == 0)
        out_loss[0] = ((red[0] + red[1]) + (red[2] + red[3])) * scale;
}

extern "C" void kernel_launch(void* const* d_in, const int* in_sizes, int n_in,
                              void* d_out, int out_size, void* d_ws, size_t ws_size,
                              hipStream_t stream) {
    const float* x = (const float*)d_in[0];
    const float* w = (const float*)d_in[1];
    float* out = (float*)d_out;
    const int xsz = in_sizes[0];   // N * D
    const int wsz = in_sizes[1];   // K * D
    const int N   = xsz / EMB_D;   // 65536
    const int K   = wsz / EMB_D;   // 1024
    const int NB  = N / 64;        // 1024

    // ws: [scount 64i][slist Ni][fidx Ni][wsq Kf][blockloss NBf]
    //     [xhi N*64 u16][xlo N*64 u16][whi K*64 u16][wlo K*64 u16]
    int*   scount    = (int*)d_ws;
    int*   slist     = scount + 64;
    int*   fidx      = slist + N;
    float* wsq       = (float*)(fidx + N);
    float* blockloss = wsq + K;
    unsigned short* xhi = (unsigned short*)(blockloss + NB);
    unsigned short* xlo = xhi + (size_t)N * EMB_D;
    unsigned short* whi = xlo + (size_t)N * EMB_D;
    unsigned short* wlo = whi + (size_t)K * EMB_D;

    const int xn4 = xsz / 4, wn4 = wsz / 4;
    vq_prep_kernel<<<(xn4 + 255) / 256, 256, 0, stream>>>(x, xhi, xlo, xn4, scount);
    vq_prep_kernel<<<(wn4 + 255) / 256, 256, 0, stream>>>(w, whi, wlo, wn4, nullptr);
    vq_wsq_kernel<<<(K + 255) / 256, 256, 0, stream>>>(w, wsq, K);
    vq_screen_kernel<<<NB, 256, 0, stream>>>(xhi, xlo, whi, wlo, wsq, fidx,
                                             slist, scount, K, N);
    vq_rescore_kernel<<<NB, 256, 0, stream>>>(x, w, wsq, fidx, slist, scount, K);
    vq_gather_kernel<<<NB, 256, 0, stream>>>(x, w, fidx, out, blockloss, N);
    vq_loss_kernel<<<1, 256, 0, stream>>>(blockloss, NB,
                                          out + (size_t)N * EMB_D + N,
                                          1.25f / (float)xsz);
}

// Round 10
// 248.443 us; speedup vs baseline: 2.9088x; 1.2378x over previous
//
#include <hip/hip_runtime.h>
#include <math.h>

#define EMB_D 64
#define MARGIN 6.0e-5f   // ref fp32-rounding band (~1.6e-5) + screen err (~6e-6), 2x slack

typedef float  f32x4  __attribute__((ext_vector_type(4)));
typedef short  bf16x8 __attribute__((ext_vector_type(8)));

__device__ __forceinline__ unsigned short f2bf(float f) {
    unsigned int u = __float_as_uint(f);
    return (unsigned short)((u + 0x7FFFu + ((u >> 16) & 1u)) >> 16);
}
__device__ __forceinline__ float bf2f(unsigned short h) {
    return __uint_as_float(((unsigned int)h) << 16);
}
// 16-B-aligned fragment load: via uint4 so LLVM emits global_load_dwordx4
// (a short8* has 2-B alignment and was being scalarized -> r9's VGPR=32).
__device__ __forceinline__ bf16x8 ldbf8(const unsigned short* p) {
    union { uint4 u; bf16x8 v; } c;
    c.u = *(const uint4*)p;
    return c.v;
}

// ---------------------------------------------------------------------------
// Prep: fp32 -> bf16 hi + lo split; zeroes the pair/full counters once.
// ---------------------------------------------------------------------------
__global__ __launch_bounds__(256)
void vq_prep_kernel(const float* __restrict__ src, unsigned short* __restrict__ hi,
                    unsigned short* __restrict__ lo, int n4, int* zc) {
    if (zc && blockIdx.x == 0 && threadIdx.x == 0) { zc[0] = 0; zc[1] = 0; }
    int i = blockIdx.x * 256 + threadIdx.x;
    if (i >= n4) return;
    float4 v = ((const float4*)src)[i];
    ushort4 h, l;
    h.x = f2bf(v.x); l.x = f2bf(v.x - bf2f(h.x));
    h.y = f2bf(v.y); l.y = f2bf(v.y - bf2f(h.y));
    h.z = f2bf(v.z); l.z = f2bf(v.z - bf2f(h.z));
    h.w = f2bf(v.w); l.w = f2bf(v.w - bf2f(h.w));
    ((ushort4*)hi)[i] = h;
    ((ushort4*)lo)[i] = l;
}

// ---------------------------------------------------------------------------
// wsq[k] = numpy-emulated fp32 sum(w_k^2).  [proven]
// ---------------------------------------------------------------------------
__global__ __launch_bounds__(256)
void vq_wsq_kernel(const float* __restrict__ w, float* __restrict__ wsq, int K) {
    int k = blockIdx.x * 256 + threadIdx.x;
    if (k >= K) return;
    const float* wr = w + (size_t)k * EMB_D;
    float r[8];
#pragma unroll
    for (int j = 0; j < 8; ++j) r[j] = __fmul_rn(wr[j], wr[j]);
#pragma unroll
    for (int t = 1; t < 8; ++t)
#pragma unroll
        for (int j = 0; j < 8; ++j)
            r[j] = __fadd_rn(r[j], __fmul_rn(wr[t * 8 + j], wr[t * 8 + j]));
    float a = __fadd_rn(__fadd_rn(r[0], r[1]), __fadd_rn(r[2], r[3]));
    float b = __fadd_rn(__fadd_rn(r[4], r[5]), __fadd_rn(r[6], r[7]));
    wsq[k] = __fadd_rn(a, b);
}

// ---------------------------------------------------------------------------
// MFMA SCREEN (r9-proven layout/arithmetic; aligned loads; top-2-with-k2 and
// top-3 merge).  Routes each row to: certain / pair-rescore / full-rescore.
// ---------------------------------------------------------------------------
__global__ __launch_bounds__(256, 4)
void vq_screen_kernel(const unsigned short* __restrict__ xhi,
                      const unsigned short* __restrict__ xlo,
                      const unsigned short* __restrict__ whi,
                      const unsigned short* __restrict__ wlo,
                      const float* __restrict__ wsq, int* __restrict__ fidx,
                      int4* __restrict__ plist, int* __restrict__ flist,
                      int* __restrict__ cnts, int K, int N) {
    const int tid  = threadIdx.x;
    const int lane = tid & 63;
    const int wave = tid >> 6;
    const int quad = lane >> 4;
    const int c16  = lane & 15;
    const int rowbase = blockIdx.x * 64 + wave * 16;

    const size_t arow = (size_t)(rowbase + c16) * EMB_D + quad * 8;
    const bf16x8 ahi0 = ldbf8(xhi + arow);
    const bf16x8 ahi1 = ldbf8(xhi + arow + 32);
    const bf16x8 alo0 = ldbf8(xlo + arow);
    const bf16x8 alo1 = ldbf8(xlo + arow + 32);

    float s1[4], s2[4];
    int   k1[4], k2[4];
#pragma unroll
    for (int i = 0; i < 4; ++i) {
        s1[i] = INFINITY; s2[i] = INFINITY; k1[i] = 0; k2[i] = 0;
    }

    const int ntile = K >> 4;
    for (int t = 0; t < ntile; ++t) {
        const size_t brow = (size_t)(t * 16 + c16) * EMB_D + quad * 8;
        const bf16x8 bhi0 = ldbf8(whi + brow);
        const bf16x8 bhi1 = ldbf8(whi + brow + 32);
        const bf16x8 blo0 = ldbf8(wlo + brow);
        const bf16x8 blo1 = ldbf8(wlo + brow + 32);
        f32x4 acc = {0.f, 0.f, 0.f, 0.f};
        acc = __builtin_amdgcn_mfma_f32_16x16x32_bf16(alo0, bhi0, acc, 0, 0, 0);
        acc = __builtin_amdgcn_mfma_f32_16x16x32_bf16(ahi0, blo0, acc, 0, 0, 0);
        acc = __builtin_amdgcn_mfma_f32_16x16x32_bf16(ahi0, bhi0, acc, 0, 0, 0);
        acc = __builtin_amdgcn_mfma_f32_16x16x32_bf16(alo1, bhi1, acc, 0, 0, 0);
        acc = __builtin_amdgcn_mfma_f32_16x16x32_bf16(ahi1, blo1, acc, 0, 0, 0);
        acc = __builtin_amdgcn_mfma_f32_16x16x32_bf16(ahi1, bhi1, acc, 0, 0, 0);

        const float wq = wsq[t * 16 + c16];
        const int   kk = t * 16 + c16;      // strictly increasing per lane
#pragma unroll
        for (int i = 0; i < 4; ++i) {
            const float s = fmaf(-2.0f, acc[i], wq);
            if (s < s1[i]) {
                s2[i] = s1[i]; k2[i] = k1[i]; s1[i] = s; k1[i] = kk;
            } else if (s < s2[i]) {
                s2[i] = s; k2[i] = kk;
            }
        }
    }

    __shared__ float M1[4][16][16], M2[4][16][16];
    __shared__ int   N1[4][16][16], N2[4][16][16];
#pragma unroll
    for (int i = 0; i < 4; ++i) {
        const int r16 = quad * 4 + i;
        M1[wave][r16][c16] = s1[i];  N1[wave][r16][c16] = k1[i];
        M2[wave][r16][c16] = s2[i];  N2[wave][r16][c16] = k2[i];
    }
    __syncthreads();
    if (lane < 16) {
        float g1 = INFINITY, g2 = INFINITY, g3 = INFINITY;
        int   gk1 = 0, gk2 = 0;
#pragma unroll
        for (int c = 0; c < 16; ++c) {
#pragma unroll
            for (int h = 0; h < 2; ++h) {
                const float s = h == 0 ? M1[wave][lane][c] : M2[wave][lane][c];
                const int   k = h == 0 ? N1[wave][lane][c] : N2[wave][lane][c];
                if (s < g1)      { g3 = g2; g2 = g1; gk2 = gk1; g1 = s; gk1 = k; }
                else if (s < g2) { g3 = g2; g2 = s; gk2 = k; }
                else if (s < g3) { g3 = s; }
            }
        }
        const int row = rowbase + lane;
        fidx[row] = gk1;
        if (g2 - g1 <= MARGIN) {              // ambiguous at screen precision
            if (g3 - g1 > MARGIN) {           // only top-2 can win -> pair test
                int p = atomicAdd(&cnts[0], 1);
                plist[p] = make_int4(row, gk1, gk2, 0);
            } else {                           // rare: 3+ in band -> full scan
                int p = atomicAdd(&cnts[1], 1);
                flist[p] = row;
            }
        }
    }
}

// ---------------------------------------------------------------------------
// PAIR RESCORE: one thread per ambiguous row; exact (f64 dot -> f32 -> numpy
// chain, proven) scores of the two candidates only.  Streams x in float4
// chunks — no 64-float register array (the r3-r8 spill lesson).
// numpy x_sq 8-acc mapping: element e=4q+c -> j=(q&1)*4+c, t=q>>1 (ascending).
// ---------------------------------------------------------------------------
__global__ __launch_bounds__(64, 1)
void vq_pair_kernel(const float* __restrict__ x, const float* __restrict__ w,
                    const float* __restrict__ wsq, int* __restrict__ fidx,
                    const int4* __restrict__ plist, const int* __restrict__ cnts) {
    const int cnt = cnts[0];
    for (int i = blockIdx.x * 64 + threadIdx.x; i < cnt; i += gridDim.x * 64) {
        const int4 e  = plist[i];
        const int row = e.x, ka = e.y, kb = e.z;
        const float4* xp = (const float4*)(x + (size_t)row * EMB_D);
        const float4* wa = (const float4*)(w + (size_t)ka * EMB_D);
        const float4* wb = (const float4*)(w + (size_t)kb * EMB_D);
        float r[8];
        double aa0 = 0, aa1 = 0, aa2 = 0, aa3 = 0;
        double ab0 = 0, ab1 = 0, ab2 = 0, ab3 = 0;
#pragma unroll
        for (int q = 0; q < 16; ++q) {
            const float4 xv = xp[q], va = wa[q], vb = wb[q];
            const int j = (q & 1) * 4;
            if (q < 2) {
                r[j + 0] = __fmul_rn(xv.x, xv.x);
                r[j + 1] = __fmul_rn(xv.y, xv.y);
                r[j + 2] = __fmul_rn(xv.z, xv.z);
                r[j + 3] = __fmul_rn(xv.w, xv.w);
            } else {
                r[j + 0] = __fadd_rn(r[j + 0], __fmul_rn(xv.x, xv.x));
                r[j + 1] = __fadd_rn(r[j + 1], __fmul_rn(xv.y, xv.y));
                r[j + 2] = __fadd_rn(r[j + 2], __fmul_rn(xv.z, xv.z));
                r[j + 3] = __fadd_rn(r[j + 3], __fmul_rn(xv.w, xv.w));
            }
            aa0 = fma((double)xv.x, (double)va.x, aa0);
            aa1 = fma((double)xv.y, (double)va.y, aa1);
            aa2 = fma((double)xv.z, (double)va.z, aa2);
            aa3 = fma((double)xv.w, (double)va.w, aa3);
            ab0 = fma((double)xv.x, (double)vb.x, ab0);
            ab1 = fma((double)xv.y, (double)vb.y, ab1);
            ab2 = fma((double)xv.z, (double)vb.z, ab2);
            ab3 = fma((double)xv.w, (double)vb.w, ab3);
        }
        const float xsq = __fadd_rn(
            __fadd_rn(__fadd_rn(r[0], r[1]), __fadd_rn(r[2], r[3])),
            __fadd_rn(__fadd_rn(r[4], r[5]), __fadd_rn(r[6], r[7])));
        const float mfa = (float)((aa0 + aa1) + (aa2 + aa3));
        const float mfb = (float)((ab0 + ab1) + (ab2 + ab3));
        const float sa = __fadd_rn(__fsub_rn(xsq, __fmul_rn(2.0f, mfa)), wsq[ka]);
        const float sb = __fadd_rn(__fsub_rn(xsq, __fmul_rn(2.0f, mfb)), wsq[kb]);
        // np.argmin: strict winner, equal -> lower index
        int win = ka;
        if (sb < sa || (sb == sa && kb < ka)) win = kb;
        fidx[row] = win;
    }
}

// ---------------------------------------------------------------------------
// FULL RESCORE (r9-proven, verbatim; reads flist/cnts[1]).  ~tens of rows.
// ---------------------------------------------------------------------------
__global__ __launch_bounds__(256, 4)
void vq_rescore_kernel(const float* __restrict__ x, const float* __restrict__ w,
                       const float* __restrict__ wsq, int* __restrict__ fidx,
                       const int* __restrict__ flist,
                       const int* __restrict__ cnts, int K) {
    const int tid  = threadIdx.x;
    const int lane = tid & 63;
    const int wave = tid >> 6;
    const int cnt  = cnts[1];

    __shared__ float4 xs4[16];
    __shared__ float  xsqs;
    __shared__ float  ls[256];
    __shared__ int    lk[256];

    for (int si = blockIdx.x; si < cnt; si += gridDim.x) {
        const int row = flist[si];
        if (tid < 16) xs4[tid] = ((const float4*)(x + (size_t)row * EMB_D))[tid];
        __syncthreads();
        if (tid == 0) {
            const float* xf = (const float*)xs4;
            float r[8];
#pragma unroll
            for (int j = 0; j < 8; ++j) r[j] = __fmul_rn(xf[j], xf[j]);
#pragma unroll
            for (int t = 1; t < 8; ++t)
#pragma unroll
                for (int j = 0; j < 8; ++j)
                    r[j] = __fadd_rn(r[j], __fmul_rn(xf[t * 8 + j], xf[t * 8 + j]));
            xsqs = __fadd_rn(
                __fadd_rn(__fadd_rn(r[0], r[1]), __fadd_rn(r[2], r[3])),
                __fadd_rn(__fadd_rn(r[4], r[5]), __fadd_rn(r[6], r[7])));
        }
        __syncthreads();
        const float xsq = xsqs;

        float bs = INFINITY;
        int   bk = K;
        for (int t = 0; t < 4; ++t) {
            const int k = wave * (K >> 2) + t * 64 + lane;
            const float4* wr4 = (const float4*)(w + (size_t)k * EMB_D);
            double a0 = 0.0, a1 = 0.0, a2 = 0.0, a3 = 0.0;
#pragma unroll
            for (int q = 0; q < EMB_D / 4; ++q) {
                const float4 xv = xs4[q];
                const float4 wv = wr4[q];
                a0 = fma((double)xv.x, (double)wv.x, a0);
                a1 = fma((double)xv.y, (double)wv.y, a1);
                a2 = fma((double)xv.z, (double)wv.z, a2);
                a3 = fma((double)xv.w, (double)wv.w, a3);
            }
            const float mf = (float)((a0 + a1) + (a2 + a3));
            const float t2 = __fsub_rn(xsq, __fmul_rn(2.0f, mf));
            const float sc = __fadd_rn(t2, wsq[k]);
            if (sc < bs || (sc == bs && k < bk)) { bs = sc; bk = k; }
        }

        ls[tid] = bs; lk[tid] = bk;
        __syncthreads();
        if (wave == 0) {
            float gs = ls[lane];
            int   gk = lk[lane];
#pragma unroll
            for (int c = 1; c < 4; ++c) {
                const float os = ls[c * 64 + lane];
                const int   ok = lk[c * 64 + lane];
                if (os < gs || (os == gs && ok < gk)) { gs = os; gk = ok; }
            }
#pragma unroll
            for (int off = 32; off > 0; off >>= 1) {
                const float os = __shfl_down(gs, off);
                const int   ok = __shfl_down(gk, off);
                if (os < gs || (os == gs && ok < gk)) { gs = os; gk = ok; }
            }
            if (lane == 0) fidx[row] = gk;
        }
        __syncthreads();
    }
}

// ---------------------------------------------------------------------------
// gather + loss partials.  [proven]
// ---------------------------------------------------------------------------
__global__ __launch_bounds__(256)
void vq_gather_kernel(const float* __restrict__ x, const float* __restrict__ w,
                      const int* __restrict__ fidx, float* __restrict__ out,
                      float* __restrict__ blockloss, int N) {
    const int tid  = threadIdx.x;
    const int lane = tid & 63;
    const int wave = tid >> 6;
    __shared__ int kf[64];
    if (tid < 64) {
        int row = blockIdx.x * 64 + tid;
        int k = fidx[row];
        kf[tid] = k;
        out[(size_t)N * EMB_D + row] = (float)k;
    }
    __syncthreads();

    float lpart = 0.f;
#pragma unroll
    for (int rep = 0; rep < 4; ++rep) {
        int f4   = rep * 256 + tid;
        int rr   = f4 >> 4;
        int c    = f4 & 15;
        int k    = kf[rr];
        int grow = blockIdx.x * 64 + rr;
        float4 wv = ((const float4*)(w + (size_t)k * EMB_D))[c];
        float4 xq = ((const float4*)(x + (size_t)grow * EMB_D))[c];
        ((float4*)out)[(size_t)grow * (EMB_D / 4) + c] = wv;
        float dx = wv.x - xq.x, dy = wv.y - xq.y;
        float dz = wv.z - xq.z, dw = wv.w - xq.w;
        lpart += dx * dx + dy * dy + dz * dz + dw * dw;
    }
#pragma unroll
    for (int off = 32; off > 0; off >>= 1) lpart += __shfl_down(lpart, off);
    __shared__ float lred[4];
    if (lane == 0) lred[wave] = lpart;
    __syncthreads();
    if (tid == 0)
        blockloss[blockIdx.x] = (lred[0] + lred[1]) + (lred[2] + lred[3]);
}

__global__ __launch_bounds__(256)
void vq_loss_kernel(const float* __restrict__ part, int nb,
                    float* __restrict__ out_loss, float scale) {
    float s = 0.f;
    for (int i = threadIdx.x; i < nb; i += 256) s += part[i];
#pragma unroll
    for (int off = 32; off > 0; off >>= 1) s += __shfl_down(s, off);
    __shared__ float red[4];
    int lane = threadIdx.x & 63, wave = threadIdx.x >> 6;
    if (lane == 0) red[wave] = s;
    __syncthreads();
    if (threadIdx.x == 0)
        out_loss[0] = ((red[0] + red[1]) + (red[2] + red[3])) * scale;
}

extern "C" void kernel_launch(void* const* d_in, const int* in_sizes, int n_in,
                              void* d_out, int out_size, void* d_ws, size_t ws_size,
                              hipStream_t stream) {
    const float* x = (const float*)d_in[0];
    const float* w = (const float*)d_in[1];
    float* out = (float*)d_out;
    const int xsz = in_sizes[0];   // N * D
    const int wsz = in_sizes[1];   // K * D
    const int N   = xsz / EMB_D;   // 65536
    const int K   = wsz / EMB_D;   // 1024
    const int NB  = N / 64;        // 1024

    // ws: [cnts 64i][plist N int4][flist Ni][fidx Ni][wsq Kf][blockloss NBf]
    //     [xhi][xlo][whi][wlo]
    int*  cnts  = (int*)d_ws;
    int4* plist = (int4*)(cnts + 64);
    int*  flist = (int*)(plist + N);
    int*  fidx  = flist + N;
    float* wsq       = (float*)(fidx + N);
    float* blockloss = wsq + K;
    unsigned short* xhi = (unsigned short*)(blockloss + NB);
    unsigned short* xlo = xhi + (size_t)N * EMB_D;
    unsigned short* whi = xlo + (size_t)N * EMB_D;
    unsigned short* wlo = whi + (size_t)K * EMB_D;

    const int xn4 = xsz / 4, wn4 = wsz / 4;
    vq_prep_kernel<<<(xn4 + 255) / 256, 256, 0, stream>>>(x, xhi, xlo, xn4, cnts);
    vq_prep_kernel<<<(wn4 + 255) / 256, 256, 0, stream>>>(w, whi, wlo, wn4, nullptr);
    vq_wsq_kernel<<<(K + 255) / 256, 256, 0, stream>>>(w, wsq, K);
    vq_screen_kernel<<<NB, 256, 0, stream>>>(xhi, xlo, whi, wlo, wsq, fidx,
                                             plist, flist, cnts, K, N);
    vq_pair_kernel<<<64, 64, 0, stream>>>(x, w, wsq, fidx, plist, cnts);
    vq_rescore_kernel<<<256, 256, 0, stream>>>(x, w, wsq, fidx, flist, cnts, K);
    vq_gather_kernel<<<NB, 256, 0, stream>>>(x, w, fidx, out, blockloss, N);
    vq_loss_kernel<<<1, 256, 0, stream>>>(blockloss, NB,
                                          out + (size_t)N * EMB_D + N,
                                          1.25f / (float)xsz);
}

// Round 11
// 177.983 us; speedup vs baseline: 4.0604x; 1.3959x over previous
//
#include <hip/hip_runtime.h>
#include <math.h>

#define EMB_D 64
#define MARGIN 6.0e-5f   // ref fp32-rounding band (~1.6e-5) + screen err (~6e-6), 2x slack

typedef float  f32x4  __attribute__((ext_vector_type(4)));
typedef short  bf16x8 __attribute__((ext_vector_type(8)));

__device__ __forceinline__ unsigned short f2bf(float f) {
    unsigned int u = __float_as_uint(f);
    return (unsigned short)((u + 0x7FFFu + ((u >> 16) & 1u)) >> 16);
}
__device__ __forceinline__ float bf2f(unsigned short h) {
    return __uint_as_float(((unsigned int)h) << 16);
}
// 16-B-aligned bf16x8 load via uint4 (works for global and LDS pointers)
__device__ __forceinline__ bf16x8 ldbf8(const unsigned short* p) {
    union { uint4 u; bf16x8 v; } c;
    c.u = *(const uint4*)p;
    return c.v;
}

// ---------------------------------------------------------------------------
// Prep: fp32 -> bf16 hi + lo split.  [proven]
// ---------------------------------------------------------------------------
__global__ __launch_bounds__(256)
void vq_prep_kernel(const float* __restrict__ src, unsigned short* __restrict__ hi,
                    unsigned short* __restrict__ lo, int n4) {
    int i = blockIdx.x * 256 + threadIdx.x;
    if (i >= n4) return;
    float4 v = ((const float4*)src)[i];
    ushort4 h, l;
    h.x = f2bf(v.x); l.x = f2bf(v.x - bf2f(h.x));
    h.y = f2bf(v.y); l.y = f2bf(v.y - bf2f(h.y));
    h.z = f2bf(v.z); l.z = f2bf(v.z - bf2f(h.z));
    h.w = f2bf(v.w); l.w = f2bf(v.w - bf2f(h.w));
    ((ushort4*)hi)[i] = h;
    ((ushort4*)lo)[i] = l;
}

// ---------------------------------------------------------------------------
// wsq[k] = numpy-emulated fp32 sum(w_k^2).  [proven]
// ---------------------------------------------------------------------------
__global__ __launch_bounds__(256)
void vq_wsq_kernel(const float* __restrict__ w, float* __restrict__ wsq, int K) {
    int k = blockIdx.x * 256 + threadIdx.x;
    if (k >= K) return;
    const float* wr = w + (size_t)k * EMB_D;
    float r[8];
#pragma unroll
    for (int j = 0; j < 8; ++j) r[j] = __fmul_rn(wr[j], wr[j]);
#pragma unroll
    for (int t = 1; t < 8; ++t)
#pragma unroll
        for (int j = 0; j < 8; ++j)
            r[j] = __fadd_rn(r[j], __fmul_rn(wr[t * 8 + j], wr[t * 8 + j]));
    float a = __fadd_rn(__fadd_rn(r[0], r[1]), __fadd_rn(r[2], r[3]));
    float b = __fadd_rn(__fadd_rn(r[4], r[5]), __fadd_rn(r[6], r[7]));
    wsq[k] = __fadd_rn(a, b);
}

// ---------------------------------------------------------------------------
// MFMA SCREEN — r10-proven arithmetic; NEW data path: w tiles staged in LDS
// once per block (pipelined one tile ahead), padded stride 72 (16-B aligned
// frags, <=2-way banks); wsq in LDS; 6-MFMA chain split 3+3.
// Routes per-row status: 0 certain / 1 pair (k2arr) / 2 full.
// ---------------------------------------------------------------------------
__global__ __launch_bounds__(256, 4)
void vq_screen_kernel(const unsigned short* __restrict__ xhi,
                      const unsigned short* __restrict__ xlo,
                      const unsigned short* __restrict__ whi,
                      const unsigned short* __restrict__ wlo,
                      const float* __restrict__ wsq, int* __restrict__ fidx,
                      int* __restrict__ status, int* __restrict__ k2arr,
                      int K, int N) {
    const int tid  = threadIdx.x;
    const int lane = tid & 63;
    const int wave = tid >> 6;
    const int quad = lane >> 4;
    const int c16  = lane & 15;
    const int rowbase = blockIdx.x * 64 + wave * 16;

    __shared__ unsigned short whi_t[16][72];   // 16 k-rows x 64 cols (+8 pad)
    __shared__ unsigned short wlo_t[16][72];
    __shared__ float wsq_lds[1024];
    __shared__ float M1[4][16][17], M2[4][16][17];
    __shared__ int   N1[4][16][17], N2[4][16][17];

    // A-frags (r10 verbatim addressing)
    const size_t arow = (size_t)(rowbase + c16) * EMB_D + quad * 8;
    const bf16x8 ahi0 = ldbf8(xhi + arow);
    const bf16x8 ahi1 = ldbf8(xhi + arow + 32);
    const bf16x8 alo0 = ldbf8(xlo + arow);
    const bf16x8 alo1 = ldbf8(xlo + arow + 32);

    // wsq -> LDS (bit-identical copy)
    ((float4*)wsq_lds)[tid] = ((const float4*)wsq)[tid];

    float s1[4], s2[4];
    int   k1[4], k2[4];
#pragma unroll
    for (int i = 0; i < 4; ++i) {
        s1[i] = INFINITY; s2[i] = INFINITY; k1[i] = 0; k2[i] = 0;
    }

    const int ntile = K >> 4;
    const ushort4* whi4 = (const ushort4*)whi;   // tile t: 256 ushort4
    const ushort4* wlo4 = (const ushort4*)wlo;
    ushort4 ph = whi4[tid];
    ushort4 pl = wlo4[tid];
    const int srow = tid >> 4;            // staging dest row
    const int scol = (tid & 15) * 4;      // staging dest col

    for (int t = 0; t < ntile; ++t) {
        *(ushort4*)&whi_t[srow][scol] = ph;
        *(ushort4*)&wlo_t[srow][scol] = pl;
        __syncthreads();
        if (t + 1 < ntile) {              // prefetch next tile during compute
            ph = whi4[(t + 1) * 256 + tid];
            pl = wlo4[(t + 1) * 256 + tid];
        }

        const bf16x8 bhi0 = ldbf8(&whi_t[c16][quad * 8]);
        const bf16x8 bhi1 = ldbf8(&whi_t[c16][quad * 8 + 32]);
        const bf16x8 blo0 = ldbf8(&wlo_t[c16][quad * 8]);
        const bf16x8 blo1 = ldbf8(&wlo_t[c16][quad * 8 + 32]);

        f32x4 acc0 = {0.f, 0.f, 0.f, 0.f};
        f32x4 acc1 = {0.f, 0.f, 0.f, 0.f};
        acc0 = __builtin_amdgcn_mfma_f32_16x16x32_bf16(alo0, bhi0, acc0, 0, 0, 0);
        acc1 = __builtin_amdgcn_mfma_f32_16x16x32_bf16(alo1, bhi1, acc1, 0, 0, 0);
        acc0 = __builtin_amdgcn_mfma_f32_16x16x32_bf16(ahi0, blo0, acc0, 0, 0, 0);
        acc1 = __builtin_amdgcn_mfma_f32_16x16x32_bf16(ahi1, blo1, acc1, 0, 0, 0);
        acc0 = __builtin_amdgcn_mfma_f32_16x16x32_bf16(ahi0, bhi0, acc0, 0, 0, 0);
        acc1 = __builtin_amdgcn_mfma_f32_16x16x32_bf16(ahi1, bhi1, acc1, 0, 0, 0);

        const float wq = wsq_lds[t * 16 + c16];
        const int   kk = t * 16 + c16;        // strictly increasing per lane
#pragma unroll
        for (int i = 0; i < 4; ++i) {
            const float s = fmaf(-2.0f, acc0[i] + acc1[i], wq);
            if (s < s1[i]) {
                s2[i] = s1[i]; k2[i] = k1[i]; s1[i] = s; k1[i] = kk;
            } else if (s < s2[i]) {
                s2[i] = s; k2[i] = kk;
            }
        }
        __syncthreads();
    }

    // cross-residue merge (r10 logic, padded arrays)
#pragma unroll
    for (int i = 0; i < 4; ++i) {
        const int r16 = quad * 4 + i;
        M1[wave][r16][c16] = s1[i];  N1[wave][r16][c16] = k1[i];
        M2[wave][r16][c16] = s2[i];  N2[wave][r16][c16] = k2[i];
    }
    __syncthreads();
    if (lane < 16) {
        float g1 = INFINITY, g2 = INFINITY, g3 = INFINITY;
        int   gk1 = 0, gk2 = 0;
#pragma unroll
        for (int c = 0; c < 16; ++c) {
#pragma unroll
            for (int h = 0; h < 2; ++h) {
                const float s = h == 0 ? M1[wave][lane][c] : M2[wave][lane][c];
                const int   k = h == 0 ? N1[wave][lane][c] : N2[wave][lane][c];
                if (s < g1)      { g3 = g2; g2 = g1; gk2 = gk1; g1 = s; gk1 = k; }
                else if (s < g2) { g3 = g2; g2 = s; gk2 = k; }
                else if (s < g3) { g3 = s; }
            }
        }
        const int row = rowbase + lane;
        fidx[row] = gk1;
        int st = 0;
        if (g2 - g1 <= MARGIN) st = (g3 - g1 > MARGIN) ? 1 : 2;
        status[row] = st;
        if (st == 1) k2arr[row] = gk2;
    }
}

// ---------------------------------------------------------------------------
// GATHER + fused exact resolution.  Phase 1: pair rows (r10-proven per-thread
// body).  Phase 2: full rows (r9-proven cooperative body).  Phase 3: gather,
// indices, loss partials (proven).
// ---------------------------------------------------------------------------
__global__ __launch_bounds__(256)
void vq_gather_kernel(const float* __restrict__ x, const float* __restrict__ w,
                      const float* __restrict__ wsq, const int* __restrict__ fidx,
                      const int* __restrict__ status, const int* __restrict__ k2arr,
                      float* __restrict__ out, float* __restrict__ blockloss,
                      int N, int K) {
    const int tid  = threadIdx.x;
    const int lane = tid & 63;
    const int wave = tid >> 6;
    __shared__ int kf[64];
    __shared__ int strow[64];
    if (tid < 64) {
        const int row = blockIdx.x * 64 + tid;
        kf[tid]    = fidx[row];
        strow[tid] = status[row];
    }
    __syncthreads();

    // ---- phase 1: pair rows (one thread each; r10-proven arithmetic) ----
    if (tid < 64 && strow[tid] == 1) {
        const int row = blockIdx.x * 64 + tid;
        const int ka = kf[tid], kb = k2arr[row];
        const float4* xp = (const float4*)(x + (size_t)row * EMB_D);
        const float4* wa = (const float4*)(w + (size_t)ka * EMB_D);
        const float4* wb = (const float4*)(w + (size_t)kb * EMB_D);
        float r[8];
        double aa0 = 0, aa1 = 0, aa2 = 0, aa3 = 0;
        double ab0 = 0, ab1 = 0, ab2 = 0, ab3 = 0;
#pragma unroll
        for (int q = 0; q < 16; ++q) {
            const float4 xv = xp[q], va = wa[q], vb = wb[q];
            const int j = (q & 1) * 4;
            if (q < 2) {
                r[j + 0] = __fmul_rn(xv.x, xv.x);
                r[j + 1] = __fmul_rn(xv.y, xv.y);
                r[j + 2] = __fmul_rn(xv.z, xv.z);
                r[j + 3] = __fmul_rn(xv.w, xv.w);
            } else {
                r[j + 0] = __fadd_rn(r[j + 0], __fmul_rn(xv.x, xv.x));
                r[j + 1] = __fadd_rn(r[j + 1], __fmul_rn(xv.y, xv.y));
                r[j + 2] = __fadd_rn(r[j + 2], __fmul_rn(xv.z, xv.z));
                r[j + 3] = __fadd_rn(r[j + 3], __fmul_rn(xv.w, xv.w));
            }
            aa0 = fma((double)xv.x, (double)va.x, aa0);
            aa1 = fma((double)xv.y, (double)va.y, aa1);
            aa2 = fma((double)xv.z, (double)va.z, aa2);
            aa3 = fma((double)xv.w, (double)va.w, aa3);
            ab0 = fma((double)xv.x, (double)vb.x, ab0);
            ab1 = fma((double)xv.y, (double)vb.y, ab1);
            ab2 = fma((double)xv.z, (double)vb.z, ab2);
            ab3 = fma((double)xv.w, (double)vb.w, ab3);
        }
        const float xsq = __fadd_rn(
            __fadd_rn(__fadd_rn(r[0], r[1]), __fadd_rn(r[2], r[3])),
            __fadd_rn(__fadd_rn(r[4], r[5]), __fadd_rn(r[6], r[7])));
        const float mfa = (float)((aa0 + aa1) + (aa2 + aa3));
        const float mfb = (float)((ab0 + ab1) + (ab2 + ab3));
        const float sa = __fadd_rn(__fsub_rn(xsq, __fmul_rn(2.0f, mfa)), wsq[ka]);
        const float sb = __fadd_rn(__fsub_rn(xsq, __fmul_rn(2.0f, mfb)), wsq[kb]);
        int win = ka;
        if (sb < sa || (sb == sa && kb < ka)) win = kb;
        kf[tid] = win;
    }
    __syncthreads();

    // ---- phase 2: full rows (rare; r9-proven cooperative body) ----
    __shared__ float4 xs4[16];
    __shared__ float  xsqs;
    __shared__ float  ls[256];
    __shared__ int    lk[256];
    for (int i = 0; i < 64; ++i) {
        if (strow[i] != 2) continue;                 // block-uniform (LDS)
        const int row = blockIdx.x * 64 + i;
        if (tid < 16) xs4[tid] = ((const float4*)(x + (size_t)row * EMB_D))[tid];
        __syncthreads();
        if (tid == 0) {
            const float* xf = (const float*)xs4;
            float r[8];
#pragma unroll
            for (int j = 0; j < 8; ++j) r[j] = __fmul_rn(xf[j], xf[j]);
#pragma unroll
            for (int t = 1; t < 8; ++t)
#pragma unroll
                for (int j = 0; j < 8; ++j)
                    r[j] = __fadd_rn(r[j], __fmul_rn(xf[t * 8 + j], xf[t * 8 + j]));
            xsqs = __fadd_rn(
                __fadd_rn(__fadd_rn(r[0], r[1]), __fadd_rn(r[2], r[3])),
                __fadd_rn(__fadd_rn(r[4], r[5]), __fadd_rn(r[6], r[7])));
        }
        __syncthreads();
        const float xsq = xsqs;

        float bs = INFINITY;
        int   bk = K;
        for (int t = 0; t < 4; ++t) {
            const int k = wave * (K >> 2) + t * 64 + lane;
            const float4* wr4 = (const float4*)(w + (size_t)k * EMB_D);
            double a0 = 0.0, a1 = 0.0, a2 = 0.0, a3 = 0.0;
#pragma unroll
            for (int q = 0; q < EMB_D / 4; ++q) {
                const float4 xv = xs4[q];
                const float4 wv = wr4[q];
                a0 = fma((double)xv.x, (double)wv.x, a0);
                a1 = fma((double)xv.y, (double)wv.y, a1);
                a2 = fma((double)xv.z, (double)wv.z, a2);
                a3 = fma((double)xv.w, (double)wv.w, a3);
            }
            const float mf = (float)((a0 + a1) + (a2 + a3));
            const float t2 = __fsub_rn(xsq, __fmul_rn(2.0f, mf));
            const float sc = __fadd_rn(t2, wsq[k]);
            if (sc < bs || (sc == bs && k < bk)) { bs = sc; bk = k; }
        }
        ls[tid] = bs; lk[tid] = bk;
        __syncthreads();
        if (wave == 0) {
            float gs = ls[lane];
            int   gk = lk[lane];
#pragma unroll
            for (int c = 1; c < 4; ++c) {
                const float os = ls[c * 64 + lane];
                const int   ok = lk[c * 64 + lane];
                if (os < gs || (os == gs && ok < gk)) { gs = os; gk = ok; }
            }
#pragma unroll
            for (int off = 32; off > 0; off >>= 1) {
                const float os = __shfl_down(gs, off);
                const int   ok = __shfl_down(gk, off);
                if (os < gs || (os == gs && ok < gk)) { gs = os; gk = ok; }
            }
            if (lane == 0) kf[i] = gk;
        }
        __syncthreads();
    }

    // ---- phase 3: indices + gather + loss partial (proven) ----
    if (tid < 64) {
        const int row = blockIdx.x * 64 + tid;
        out[(size_t)N * EMB_D + row] = (float)kf[tid];
    }
    float lpart = 0.f;
#pragma unroll
    for (int rep = 0; rep < 4; ++rep) {
        int f4   = rep * 256 + tid;
        int rr   = f4 >> 4;
        int c    = f4 & 15;
        int k    = kf[rr];
        int grow = blockIdx.x * 64 + rr;
        float4 wv = ((const float4*)(w + (size_t)k * EMB_D))[c];
        float4 xq = ((const float4*)(x + (size_t)grow * EMB_D))[c];
        ((float4*)out)[(size_t)grow * (EMB_D / 4) + c] = wv;
        float dx = wv.x - xq.x, dy = wv.y - xq.y;
        float dz = wv.z - xq.z, dw = wv.w - xq.w;
        lpart += dx * dx + dy * dy + dz * dz + dw * dw;
    }
#pragma unroll
    for (int off = 32; off > 0; off >>= 1) lpart += __shfl_down(lpart, off);
    __shared__ float lred[4];
    if (lane == 0) lred[wave] = lpart;
    __syncthreads();
    if (tid == 0)
        blockloss[blockIdx.x] = (lred[0] + lred[1]) + (lred[2] + lred[3]);
}

__global__ __launch_bounds__(256)
void vq_loss_kernel(const float* __restrict__ part, int nb,
                    float* __restrict__ out_loss, float scale) {
    float s = 0.f;
    for (int i = threadIdx.x; i < nb; i += 256) s += part[i];
#pragma unroll
    for (int off = 32; off > 0; off >>= 1) s += __shfl_down(s, off);
    __shared__ float red[4];
    int lane = threadIdx.x & 63, wave = threadIdx.x >> 6;
    if (lane == 0) red[wave] = s;
    __syncthreads();
    if (threadIdx.x == 0)
        out_loss[0] = ((red[0] + red[1]) + (red[2] + red[3])) * scale;
}

extern "C" void kernel_launch(void* const* d_in, const int* in_sizes, int n_in,
                              void* d_out, int out_size, void* d_ws, size_t ws_size,
                              hipStream_t stream) {
    const float* x = (const float*)d_in[0];
    const float* w = (const float*)d_in[1];
    float* out = (float*)d_out;
    const int xsz = in_sizes[0];   // N * D
    const int wsz = in_sizes[1];   // K * D
    const int N   = xsz / EMB_D;   // 65536
    const int K   = wsz / EMB_D;   // 1024
    const int NB  = N / 64;        // 1024

    // ws: [status Ni][k2arr Ni][fidx Ni][wsq Kf][blockloss NBf][xhi][xlo][whi][wlo]
    int*   status    = (int*)d_ws;
    int*   k2arr     = status + N;
    int*   fidx      = k2arr + N;
    float* wsq       = (float*)(fidx + N);
    float* blockloss = wsq + K;
    unsigned short* xhi = (unsigned short*)(blockloss + NB);
    unsigned short* xlo = xhi + (size_t)N * EMB_D;
    unsigned short* whi = xlo + (size_t)N * EMB_D;
    unsigned short* wlo = whi + (size_t)K * EMB_D;

    const int xn4 = xsz / 4, wn4 = wsz / 4;
    vq_prep_kernel<<<(xn4 + 255) / 256, 256, 0, stream>>>(x, xhi, xlo, xn4);
    vq_prep_kernel<<<(wn4 + 255) / 256, 256, 0, stream>>>(w, whi, wlo, wn4);
    vq_wsq_kernel<<<(K + 255) / 256, 256, 0, stream>>>(w, wsq, K);
    vq_screen_kernel<<<NB, 256, 0, stream>>>(xhi, xlo, whi, wlo, wsq, fidx,
                                             status, k2arr, K, N);
    vq_gather_kernel<<<NB, 256, 0, stream>>>(x, w, wsq, fidx, status, k2arr,
                                             out, blockloss, N, K);
    vq_loss_kernel<<<1, 256, 0, stream>>>(blockloss, NB,
                                          out + (size_t)N * EMB_D + N,
                                          1.25f / (float)xsz);
}

// Round 12
// 147.565 us; speedup vs baseline: 4.8974x; 1.2061x over previous
//
#include <hip/hip_runtime.h>
#include <math.h>

#define EMB_D 64
#define MARGIN 6.0e-5f   // ref fp32-rounding band (~1.6e-5) + screen err (~6e-6), 2x slack

typedef float  f32x4  __attribute__((ext_vector_type(4)));
typedef short  bf16x8 __attribute__((ext_vector_type(8)));

__device__ __forceinline__ unsigned short f2bf(float f) {
    unsigned int u = __float_as_uint(f);
    return (unsigned short)((u + 0x7FFFu + ((u >> 16) & 1u)) >> 16);
}
__device__ __forceinline__ float bf2f(unsigned short h) {
    return __uint_as_float(((unsigned int)h) << 16);
}

union Pack8 { ushort u[8]; bf16x8 v; uint4 q; };

// 16-B-aligned bf16x8 load (LDS or global) via uint4
__device__ __forceinline__ bf16x8 ldbf8(const unsigned short* p) {
    union { uint4 u; bf16x8 v; } c;
    c.u = *(const uint4*)p;
    return c.v;
}

// ---------------------------------------------------------------------------
// PREP-W: w -> bf16 hi/lo in MFMA-chunk-transposed order + wsq + zero loss.
// Chunk c = kb*512 + s*128 + q*16 + r  holds w row (kb*64+s*16+r),
// cols q*8..q*8+7 (kb=64-k segment, s=16-k subtile, q=col chunk, r=row).
// Screen then reads B-frag (c16,quad,h) at chunk s*128+h*64+lane — linear.
// ---------------------------------------------------------------------------
__global__ __launch_bounds__(256)
void vq_prepw_kernel(const float* __restrict__ w,
                     unsigned short* __restrict__ wt_hi,
                     unsigned short* __restrict__ wt_lo,
                     float* __restrict__ wsq, float* __restrict__ loss_out,
                     int K) {
    const int i = blockIdx.x * 256 + threadIdx.x;   // chunk id, K*8 total
    if (i == 0) loss_out[0] = 0.f;
    if (i >= K * 8) return;
    const int krow = i >> 3, q = i & 7;
    const int dest = ((krow >> 6) << 9) + (((krow >> 4) & 3) << 7) + (q << 4)
                   + (krow & 15);
    const float* src = w + (size_t)krow * EMB_D + q * 8;
    Pack8 h, l;
#pragma unroll
    for (int j = 0; j < 8; ++j) {
        const float f = src[j];
        h.u[j] = f2bf(f);
        l.u[j] = f2bf(f - bf2f(h.u[j]));
    }
    ((uint4*)wt_hi)[dest] = h.q;
    ((uint4*)wt_lo)[dest] = l.q;

    if (i < K) {   // wsq[i]: numpy-emulated fp32 sum(w_i^2)  [proven]
        const float* wr = w + (size_t)i * EMB_D;
        float r[8];
#pragma unroll
        for (int j = 0; j < 8; ++j) r[j] = __fmul_rn(wr[j], wr[j]);
#pragma unroll
        for (int t = 1; t < 8; ++t)
#pragma unroll
            for (int j = 0; j < 8; ++j)
                r[j] = __fadd_rn(r[j], __fmul_rn(wr[t * 8 + j], wr[t * 8 + j]));
        float a = __fadd_rn(__fadd_rn(r[0], r[1]), __fadd_rn(r[2], r[3]));
        float b = __fadd_rn(__fadd_rn(r[4], r[5]), __fadd_rn(r[6], r[7]));
        wsq[i] = __fadd_rn(a, b);
    }
}

// ---------------------------------------------------------------------------
// MFMA SCREEN — r11-proven arithmetic (same MFMA order/operands -> bit-equal
// scores).  New data path: in-register x hi/lo split (no prep-x kernel, no
// 64-float array); 64-k segments staged via linear conflict-free chunks
// (16 barrier pairs instead of 64); branch-free med3 top-2.
// ---------------------------------------------------------------------------
__global__ __launch_bounds__(256, 4)
void vq_screen_kernel(const float* __restrict__ x,
                      const unsigned short* __restrict__ wt_hi,
                      const unsigned short* __restrict__ wt_lo,
                      const float* __restrict__ wsq, int* __restrict__ fidx,
                      int* __restrict__ status, int* __restrict__ k2arr,
                      int K, int N) {
    const int tid  = threadIdx.x;
    const int lane = tid & 63;
    const int wave = tid >> 6;
    const int quad = lane >> 4;
    const int c16  = lane & 15;
    const int rowbase = blockIdx.x * 64 + wave * 16;

    __shared__ uint4 sh4[512];          // hi chunks, 8 KB
    __shared__ uint4 sl4[512];          // lo chunks, 8 KB
    __shared__ float wsq_lds[1024];
    __shared__ float M1[4][16][17], M2[4][16][17];
    __shared__ int   N1[4][16][17], N2[4][16][17];

    // ---- A-frags: split x hi/lo in-register (this lane's 16 floats only) ----
    const float* xrow = x + (size_t)(rowbase + c16) * EMB_D + quad * 8;
    Pack8 ah0, al0, ah1, al1;
#pragma unroll
    for (int j = 0; j < 8; ++j) {
        const float f0 = xrow[j];
        ah0.u[j] = f2bf(f0); al0.u[j] = f2bf(f0 - bf2f(ah0.u[j]));
        const float f1 = xrow[32 + j];
        ah1.u[j] = f2bf(f1); al1.u[j] = f2bf(f1 - bf2f(ah1.u[j]));
    }
    const bf16x8 ahi0 = ah0.v, alo0 = al0.v, ahi1 = ah1.v, alo1 = al1.v;

    ((float4*)wsq_lds)[tid] = ((const float4*)wsq)[tid];

    float s1[4], s2[4];
    int   k1[4], k2[4];
#pragma unroll
    for (int i = 0; i < 4; ++i) {
        s1[i] = INFINITY; s2[i] = INFINITY; k1[i] = 0; k2[i] = 0;
    }

    const uint4* gh = (const uint4*)wt_hi;
    const uint4* gl = (const uint4*)wt_lo;
    uint4 ph0 = gh[tid], ph1 = gh[256 + tid];
    uint4 pl0 = gl[tid], pl1 = gl[256 + tid];

    const int nseg = K >> 6;            // 16
    for (int seg = 0; seg < nseg; ++seg) {
        sh4[tid] = ph0; sh4[256 + tid] = ph1;
        sl4[tid] = pl0; sl4[256 + tid] = pl1;
        __syncthreads();
        if (seg + 1 < nseg) {           // prefetch next segment (coalesced)
            const int b = (seg + 1) * 512;
            ph0 = gh[b + tid]; ph1 = gh[b + 256 + tid];
            pl0 = gl[b + tid]; pl1 = gl[b + 256 + tid];
        }

#pragma unroll
        for (int s = 0; s < 4; ++s) {
            // frag chunks: s*128 + h*64 + lane  (lane = quad*16 + c16)
            const unsigned short* shp = (const unsigned short*)sh4;
            const unsigned short* slp = (const unsigned short*)sl4;
            const bf16x8 bhi0 = ldbf8(shp + (s * 128 + lane) * 8);
            const bf16x8 bhi1 = ldbf8(shp + (s * 128 + 64 + lane) * 8);
            const bf16x8 blo0 = ldbf8(slp + (s * 128 + lane) * 8);
            const bf16x8 blo1 = ldbf8(slp + (s * 128 + 64 + lane) * 8);

            f32x4 acc0 = {0.f, 0.f, 0.f, 0.f};
            f32x4 acc1 = {0.f, 0.f, 0.f, 0.f};
            acc0 = __builtin_amdgcn_mfma_f32_16x16x32_bf16(alo0, bhi0, acc0, 0, 0, 0);
            acc1 = __builtin_amdgcn_mfma_f32_16x16x32_bf16(alo1, bhi1, acc1, 0, 0, 0);
            acc0 = __builtin_amdgcn_mfma_f32_16x16x32_bf16(ahi0, blo0, acc0, 0, 0, 0);
            acc1 = __builtin_amdgcn_mfma_f32_16x16x32_bf16(ahi1, blo1, acc1, 0, 0, 0);
            acc0 = __builtin_amdgcn_mfma_f32_16x16x32_bf16(ahi0, bhi0, acc0, 0, 0, 0);
            acc1 = __builtin_amdgcn_mfma_f32_16x16x32_bf16(ahi1, bhi1, acc1, 0, 0, 0);

            const int   kk = seg * 64 + s * 16 + c16;   // ascending per lane
            const float wq = wsq_lds[kk];
#pragma unroll
            for (int i = 0; i < 4; ++i) {
                const float sc = fmaf(-2.0f, acc0[i] + acc1[i], wq);
                // branch-free top-2 (== sequential strict-< update; s1<=s2)
                const bool c1 = sc < s1[i];
                const bool c2 = sc < s2[i];
                k2[i] = c1 ? k1[i] : (c2 ? kk : k2[i]);
                k1[i] = c1 ? kk : k1[i];
                s2[i] = __builtin_amdgcn_fmed3f(sc, s1[i], s2[i]);
                s1[i] = fminf(sc, s1[i]);
            }
        }
        __syncthreads();
    }

    // ---- cross-residue merge (r11-proven) ----
#pragma unroll
    for (int i = 0; i < 4; ++i) {
        const int r16 = quad * 4 + i;
        M1[wave][r16][c16] = s1[i];  N1[wave][r16][c16] = k1[i];
        M2[wave][r16][c16] = s2[i];  N2[wave][r16][c16] = k2[i];
    }
    __syncthreads();
    if (lane < 16) {
        float g1 = INFINITY, g2 = INFINITY, g3 = INFINITY;
        int   gk1 = 0, gk2 = 0;
#pragma unroll
        for (int c = 0; c < 16; ++c) {
#pragma unroll
            for (int h = 0; h < 2; ++h) {
                const float s = h == 0 ? M1[wave][lane][c] : M2[wave][lane][c];
                const int   k = h == 0 ? N1[wave][lane][c] : N2[wave][lane][c];
                if (s < g1)      { g3 = g2; g2 = g1; gk2 = gk1; g1 = s; gk1 = k; }
                else if (s < g2) { g3 = g2; g2 = s; gk2 = k; }
                else if (s < g3) { g3 = s; }
            }
        }
        const int row = rowbase + lane;
        fidx[row] = gk1;
        int st = 0;
        if (g2 - g1 <= MARGIN) st = (g3 - g1 > MARGIN) ? 1 : 2;
        status[row] = st;
        if (st == 1) k2arr[row] = gk2;
    }
}

// ---------------------------------------------------------------------------
// GATHER + fused exact resolution (r11-proven) + atomic loss accumulation.
// ---------------------------------------------------------------------------
__global__ __launch_bounds__(256)
void vq_gather_kernel(const float* __restrict__ x, const float* __restrict__ w,
                      const float* __restrict__ wsq, const int* __restrict__ fidx,
                      const int* __restrict__ status, const int* __restrict__ k2arr,
                      float* __restrict__ out, float* __restrict__ loss_out,
                      int N, int K, float scale) {
    const int tid  = threadIdx.x;
    const int lane = tid & 63;
    const int wave = tid >> 6;
    __shared__ int kf[64];
    __shared__ int strow[64];
    if (tid < 64) {
        const int row = blockIdx.x * 64 + tid;
        kf[tid]    = fidx[row];
        strow[tid] = status[row];
    }
    __syncthreads();

    // ---- phase 1: pair rows (r10/r11-proven per-thread exact compare) ----
    if (tid < 64 && strow[tid] == 1) {
        const int row = blockIdx.x * 64 + tid;
        const int ka = kf[tid], kb = k2arr[row];
        const float4* xp = (const float4*)(x + (size_t)row * EMB_D);
        const float4* wa = (const float4*)(w + (size_t)ka * EMB_D);
        const float4* wb = (const float4*)(w + (size_t)kb * EMB_D);
        float r[8];
        double aa0 = 0, aa1 = 0, aa2 = 0, aa3 = 0;
        double ab0 = 0, ab1 = 0, ab2 = 0, ab3 = 0;
#pragma unroll
        for (int q = 0; q < 16; ++q) {
            const float4 xv = xp[q], va = wa[q], vb = wb[q];
            const int j = (q & 1) * 4;
            if (q < 2) {
                r[j + 0] = __fmul_rn(xv.x, xv.x);
                r[j + 1] = __fmul_rn(xv.y, xv.y);
                r[j + 2] = __fmul_rn(xv.z, xv.z);
                r[j + 3] = __fmul_rn(xv.w, xv.w);
            } else {
                r[j + 0] = __fadd_rn(r[j + 0], __fmul_rn(xv.x, xv.x));
                r[j + 1] = __fadd_rn(r[j + 1], __fmul_rn(xv.y, xv.y));
                r[j + 2] = __fadd_rn(r[j + 2], __fmul_rn(xv.z, xv.z));
                r[j + 3] = __fadd_rn(r[j + 3], __fmul_rn(xv.w, xv.w));
            }
            aa0 = fma((double)xv.x, (double)va.x, aa0);
            aa1 = fma((double)xv.y, (double)va.y, aa1);
            aa2 = fma((double)xv.z, (double)va.z, aa2);
            aa3 = fma((double)xv.w, (double)va.w, aa3);
            ab0 = fma((double)xv.x, (double)vb.x, ab0);
            ab1 = fma((double)xv.y, (double)vb.y, ab1);
            ab2 = fma((double)xv.z, (double)vb.z, ab2);
            ab3 = fma((double)xv.w, (double)vb.w, ab3);
        }
        const float xsq = __fadd_rn(
            __fadd_rn(__fadd_rn(r[0], r[1]), __fadd_rn(r[2], r[3])),
            __fadd_rn(__fadd_rn(r[4], r[5]), __fadd_rn(r[6], r[7])));
        const float mfa = (float)((aa0 + aa1) + (aa2 + aa3));
        const float mfb = (float)((ab0 + ab1) + (ab2 + ab3));
        const float sa = __fadd_rn(__fsub_rn(xsq, __fmul_rn(2.0f, mfa)), wsq[ka]);
        const float sb = __fadd_rn(__fsub_rn(xsq, __fmul_rn(2.0f, mfb)), wsq[kb]);
        int win = ka;
        if (sb < sa || (sb == sa && kb < ka)) win = kb;
        kf[tid] = win;
    }
    __syncthreads();

    // ---- phase 2: full rows (rare; r9/r11-proven cooperative body) ----
    __shared__ float4 xs4[16];
    __shared__ float  xsqs;
    __shared__ float  ls[256];
    __shared__ int    lk[256];
    for (int i = 0; i < 64; ++i) {
        if (strow[i] != 2) continue;                 // block-uniform (LDS)
        const int row = blockIdx.x * 64 + i;
        if (tid < 16) xs4[tid] = ((const float4*)(x + (size_t)row * EMB_D))[tid];
        __syncthreads();
        if (tid == 0) {
            const float* xf = (const float*)xs4;
            float r[8];
#pragma unroll
            for (int j = 0; j < 8; ++j) r[j] = __fmul_rn(xf[j], xf[j]);
#pragma unroll
            for (int t = 1; t < 8; ++t)
#pragma unroll
                for (int j = 0; j < 8; ++j)
                    r[j] = __fadd_rn(r[j], __fmul_rn(xf[t * 8 + j], xf[t * 8 + j]));
            xsqs = __fadd_rn(
                __fadd_rn(__fadd_rn(r[0], r[1]), __fadd_rn(r[2], r[3])),
                __fadd_rn(__fadd_rn(r[4], r[5]), __fadd_rn(r[6], r[7])));
        }
        __syncthreads();
        const float xsq = xsqs;

        float bs = INFINITY;
        int   bk = K;
        for (int t = 0; t < 4; ++t) {
            const int k = wave * (K >> 2) + t * 64 + lane;
            const float4* wr4 = (const float4*)(w + (size_t)k * EMB_D);
            double a0 = 0.0, a1 = 0.0, a2 = 0.0, a3 = 0.0;
#pragma unroll
            for (int q = 0; q < EMB_D / 4; ++q) {
                const float4 xv = xs4[q];
                const float4 wv = wr4[q];
                a0 = fma((double)xv.x, (double)wv.x, a0);
                a1 = fma((double)xv.y, (double)wv.y, a1);
                a2 = fma((double)xv.z, (double)wv.z, a2);
                a3 = fma((double)xv.w, (double)wv.w, a3);
            }
            const float mf = (float)((a0 + a1) + (a2 + a3));
            const float t2 = __fsub_rn(xsq, __fmul_rn(2.0f, mf));
            const float sc = __fadd_rn(t2, wsq[k]);
            if (sc < bs || (sc == bs && k < bk)) { bs = sc; bk = k; }
        }
        ls[tid] = bs; lk[tid] = bk;
        __syncthreads();
        if (wave == 0) {
            float gs = ls[lane];
            int   gk = lk[lane];
#pragma unroll
            for (int c = 1; c < 4; ++c) {
                const float os = ls[c * 64 + lane];
                const int   ok = lk[c * 64 + lane];
                if (os < gs || (os == gs && ok < gk)) { gs = os; gk = ok; }
            }
#pragma unroll
            for (int off = 32; off > 0; off >>= 1) {
                const float os = __shfl_down(gs, off);
                const int   ok = __shfl_down(gk, off);
                if (os < gs || (os == gs && ok < gk)) { gs = os; gk = ok; }
            }
            if (lane == 0) kf[i] = gk;
        }
        __syncthreads();
    }

    // ---- phase 3: indices + gather + loss (atomic accumulate) ----
    if (tid < 64) {
        const int row = blockIdx.x * 64 + tid;
        out[(size_t)N * EMB_D + row] = (float)kf[tid];
    }
    float lpart = 0.f;
#pragma unroll
    for (int rep = 0; rep < 4; ++rep) {
        int f4   = rep * 256 + tid;
        int rr   = f4 >> 4;
        int c    = f4 & 15;
        int k    = kf[rr];
        int grow = blockIdx.x * 64 + rr;
        float4 wv = ((const float4*)(w + (size_t)k * EMB_D))[c];
        float4 xq = ((const float4*)(x + (size_t)grow * EMB_D))[c];
        ((float4*)out)[(size_t)grow * (EMB_D / 4) + c] = wv;
        float dx = wv.x - xq.x, dy = wv.y - xq.y;
        float dz = wv.z - xq.z, dw = wv.w - xq.w;
        lpart += dx * dx + dy * dy + dz * dz + dw * dw;
    }
#pragma unroll
    for (int off = 32; off > 0; off >>= 1) lpart += __shfl_down(lpart, off);
    __shared__ float lred[4];
    if (lane == 0) lred[wave] = lpart;
    __syncthreads();
    if (tid == 0)
        atomicAdd(loss_out, ((lred[0] + lred[1]) + (lred[2] + lred[3])) * scale);
}

extern "C" void kernel_launch(void* const* d_in, const int* in_sizes, int n_in,
                              void* d_out, int out_size, void* d_ws, size_t ws_size,
                              hipStream_t stream) {
    const float* x = (const float*)d_in[0];
    const float* w = (const float*)d_in[1];
    float* out = (float*)d_out;
    const int xsz = in_sizes[0];   // N * D
    const int wsz = in_sizes[1];   // K * D
    const int N   = xsz / EMB_D;   // 65536
    const int K   = wsz / EMB_D;   // 1024
    const int NB  = N / 64;        // 1024
    float* loss_out = out + (size_t)N * EMB_D + N;

    // ws: [status Ni][k2arr Ni][fidx Ni][wsq Kf][wt_hi K*64 u16][wt_lo K*64 u16]
    int*   status = (int*)d_ws;
    int*   k2arr  = status + N;
    int*   fidx   = k2arr + N;
    float* wsq    = (float*)(fidx + N);
    unsigned short* wt_hi = (unsigned short*)(wsq + K);
    unsigned short* wt_lo = wt_hi + (size_t)K * EMB_D;

    vq_prepw_kernel<<<(K * 8 + 255) / 256, 256, 0, stream>>>(w, wt_hi, wt_lo,
                                                             wsq, loss_out, K);
    vq_screen_kernel<<<NB, 256, 0, stream>>>(x, wt_hi, wt_lo, wsq, fidx,
                                             status, k2arr, K, N);
    vq_gather_kernel<<<NB, 256, 0, stream>>>(x, w, wsq, fidx, status, k2arr,
                                             out, loss_out, N, K,
                                             1.25f / (float)xsz);
}